// Round 9
// baseline (187.076 us; speedup 1.0000x reference)
//
#include <hip/hip_runtime.h>
#include <hip/hip_bf16.h>
#include <stdint.h>

typedef __hip_bfloat16 bf16;
typedef __attribute__((ext_vector_type(8))) short short8;   // 8 bf16
typedef __attribute__((ext_vector_type(4))) float f32x4;

#define QSCALE 0.18033688011f   // 0.125 * log2(e), folded into Q at gemm0

// ---- 1-instr helpers ----
__device__ __forceinline__ float fast_exp2(float x) {
#if __has_builtin(__builtin_amdgcn_exp2f)
  return __builtin_amdgcn_exp2f(x);
#else
  return exp2f(x);
#endif
}

__device__ __forceinline__ uint32_t pack2_bf16(float a, float b) {
#if __has_builtin(__builtin_amdgcn_cvt_pk_bf16_f32)
  typedef __attribute__((ext_vector_type(2))) __bf16 bf16x2;
  bf16x2 v = __builtin_amdgcn_cvt_pk_bf16_f32(a, b);
  return __builtin_bit_cast(uint32_t, v);
#else
  uint32_t ua = __builtin_bit_cast(uint32_t, a);
  uint32_t ub = __builtin_bit_cast(uint32_t, b);
  ua += 0x7FFF + ((ua >> 16) & 1);   // RNE
  ub += 0x7FFF + ((ub >> 16) & 1);
  return (ua >> 16) | (ub & 0xFFFF0000u);
#endif
}

// async global->LDS, 16B per lane: g is the PER-LANE global pointer,
// l is the WAVE-UNIFORM LDS base (lane lands at l + lane*16B).
__device__ __forceinline__ void gload_lds16(const bf16* g, bf16* l) {
#if __has_builtin(__builtin_amdgcn_global_load_lds)
  __builtin_amdgcn_global_load_lds(
      (const __attribute__((address_space(1))) void*)(uintptr_t)g,
      (__attribute__((address_space(3))) void*)(uint32_t)(uintptr_t)l,
      16, 0, 0);
#else
  int lane = threadIdx.x & 63;
  *(short8*)(l + lane * 8) = *(const short8*)(g + lane * 8);
#endif
}

// barrier that also waits for outstanding global_load_lds DMAs
#define DMA_BARRIER() \
  asm volatile("s_waitcnt vmcnt(0) lgkmcnt(0)\n\ts_barrier" ::: "memory")

// ---- fp32->bf16 transpose tile body (64x64) ----
__device__ __forceinline__ void transpose_tile(const float* __restrict__ in,
                                               bf16* __restrict__ out,
                                               int R, int C, int bx, int by,
                                               bf16 (*t)[72]) {
  const int r0 = by * 64, c0 = bx * 64;
  const int rr = threadIdx.x >> 3, cc = (threadIdx.x & 7) * 8;
#pragma unroll
  for (int rep = 0; rep < 2; ++rep) {
    int y = rr + rep * 32;
    const float* p = in + (size_t)(r0 + y) * C + c0 + cc;
    f32x4 v0 = *(const f32x4*)p;
    f32x4 v1 = *(const f32x4*)(p + 4);
#pragma unroll
    for (int j = 0; j < 4; ++j) {
      t[cc + j][y] = __float2bfloat16(v0[j]);
      t[cc + 4 + j][y] = __float2bfloat16(v1[j]);
    }
  }
  __syncthreads();
#pragma unroll
  for (int rep = 0; rep < 2; ++rep) {
    int y = rr + rep * 32;
    short8 v = *(const short8*)&t[y][cc];
    *(short8*)(out + (size_t)(c0 + y) * R + r0 + cc) = v;
  }
}

// ---- fused prep: x->bf16 (blocks 0..2047), Wqkv^T (2048..2815),
//      Wproj^T (2816..3071) ----
__global__ __launch_bounds__(256)
void prep_k(const float* __restrict__ x, bf16* __restrict__ xb,
            const float* __restrict__ Wqkv, bf16* __restrict__ WtQkv,
            const float* __restrict__ Wproj, bf16* __restrict__ WtP) {
  __shared__ __align__(16) bf16 t[64][72];
  const int bid = blockIdx.x;
  if (bid < 2048) {
    int i = (bid * 256 + threadIdx.x) * 8;
    f32x4 v0 = *(const f32x4*)(x + i);
    f32x4 v1 = *(const f32x4*)(x + i + 4);
    short8 r;
    bf16* rb = (bf16*)&r;
#pragma unroll
    for (int j = 0; j < 4; ++j) {
      rb[j] = __float2bfloat16(v0[j]);
      rb[4 + j] = __float2bfloat16(v1[j]);
    }
    *(short8*)(xb + i) = r;
  } else if (bid < 2048 + 768) {
    int b = bid - 2048;
    transpose_tile(Wqkv, WtQkv, 1024, 3072, b % 48, b / 48, t);
  } else {
    int b = bid - 2816;
    transpose_tile(Wproj, WtP, 1024, 1024, b % 16, b / 16, t);
  }
}

// ---------------- GEMM: C[m][n] = A[m,:]·Bt[n,:] + bias[n] -------------------
// K-loop is DOUBLE-BUFFERED with async global_load_lds: DMA for tile kt+32 is
// issued BEFORE computing tile kt, so the global->LDS latency has a full
// iteration of MFMA to hide under; one vmcnt+barrier per iteration (R8's attn
// pattern, proven). Previously the loop issued DMA then immediately drained
// vmcnt(0) at __syncthreads -> full DMA latency on the critical path x32.
// MODE 0 (TM=128): LDS-transposed coalesced epilogue -> Q (xQSCALE) as
//   [bh][t][64] (linear), K as [bh][t][64] with 16B-chunk XOR-swizzle
//   (chunk ^= row&7), V^T as [bh][64][t] with per-64-tile chunk XOR-swizzle
//   (chunk ^= d&7) -- lets attn stage K/V linearly via global_load_lds and
//   read fragments conflict-free.
// MODE 1 (TM=64): fp32 out row-major [M,Nn].
// Grid XCD-chunk swizzled (nwg % 8 == 0 -> bijective).
template <int MODE, int TM>
__global__ __launch_bounds__(256, (TM == 128) ? 3 : 2)
void gemm_bt(const bf16* __restrict__ A, const bf16* __restrict__ Bt,
             const float* __restrict__ bias, float* __restrict__ outp,
             bf16* __restrict__ Qd, bf16* __restrict__ Kd, bf16* __restrict__ Vt,
             int M, int Nn, int K) {
  constexpr int MI = TM / 32;
  constexpr int BUFE = TM * 32 + 4096;   // elements per staging buffer
  // 2 staging buffers; MODE-0 epilogue (<=9216 el) reuses the pool
  __shared__ __align__(16) bf16 smem[2 * BUFE];

  const int tid = threadIdx.x;
  const int wave = tid >> 6, lane = tid & 63;
  const int quad = lane >> 4, l16 = lane & 15;
  const int mw = (wave >> 1) * (TM / 2), nw = (wave & 1) * 64;

  // XCD-chunked swizzle of the linearized block id
  const int nwg = gridDim.x * gridDim.y;
  const int ord = blockIdx.y * gridDim.x + blockIdx.x;
  const int wg = (ord & 7) * (nwg >> 3) + (ord >> 3);
  const int m_blk = (wg / gridDim.x) * TM, n_blk = (wg % gridDim.x) * 128;

  f32x4 acc[MI][4];
#pragma unroll
  for (int i = 0; i < MI; ++i)
#pragma unroll
    for (int j = 0; j < 4; ++j) acc[i][j] = (f32x4){0.f, 0.f, 0.f, 0.f};

  const int rowA = lane >> 2, colA = (lane & 3) * 8;
  const int chunkB = wave * 2;
  const bf16* gB = Bt + (size_t)(n_blk + chunkB * 16 + rowA) * K + colA;
  const int chunkA = (TM == 128) ? wave * 2 : wave;
  const bf16* gA = A + (size_t)(m_blk + chunkA * 16 + rowA) * K + colA;

  // in-buffer LDS offsets (wave-uniform bases for the DMA)
  const int oA0 = chunkA * 512;
  const int oA1 = (chunkA + 1) * 512;             // unused for TM=64
  const int oB0 = TM * 32 + chunkB * 512;
  const int oB1 = TM * 32 + (chunkB + 1) * 512;

  // prologue: DMA tile 0 -> buffer 0
  gload_lds16(gA, smem + oA0);
  if (TM == 128) gload_lds16(gA + 16 * K, smem + oA1);
  gload_lds16(gB, smem + oB0);
  gload_lds16(gB + 16 * K, smem + oB1);
  DMA_BARRIER();

  for (int kt = 0; kt < K; kt += 32) {
    const int cur = (kt >> 5) & 1;
    bf16* bufc = smem + cur * BUFE;

    // 1. issue DMA for tile kt+32 into the other buffer (lands during MFMA)
    if (kt + 32 < K) {
      bf16* bufn = smem + (cur ^ 1) * BUFE;
      gload_lds16(gA + kt + 32, bufn + oA0);
      if (TM == 128) gload_lds16(gA + 16 * K + kt + 32, bufn + oA1);
      gload_lds16(gB + kt + 32, bufn + oB0);
      gload_lds16(gB + 16 * K + kt + 32, bufn + oB1);
    }

    // 2. compute tile kt from the current buffer
    short8 af[MI], bfv[4];
#pragma unroll
    for (int i = 0; i < MI; ++i)
      af[i] = *(const short8*)&bufc[(mw + i * 16 + l16) * 32 + quad * 8];
#pragma unroll
    for (int j = 0; j < 4; ++j)
      bfv[j] = *(const short8*)&bufc[TM * 32 + (nw + j * 16 + l16) * 32 + quad * 8];
#pragma unroll
    for (int i = 0; i < MI; ++i)
#pragma unroll
      for (int j = 0; j < 4; ++j)
        acc[i][j] = __builtin_amdgcn_mfma_f32_16x16x32_bf16(af[i], bfv[j],
                                                            acc[i][j], 0, 0, 0);

    // 3. one barrier: this iter's reads done + next tile's DMA landed
    DMA_BARRIER();
  }

  if (MODE == 0) {
    // per-j bias for this wave's columns
    float bval[4];
#pragma unroll
    for (int j = 0; j < 4; ++j) bval[j] = bias[n_blk + nw + j * 16 + l16];

    const int part = n_blk >> 10;          // 0:q 1:k 2:v (block-uniform)
    const int b = m_blk >> 11;
    const int tloc = m_blk & 2047;
    const int h0 = (n_blk & 1023) >> 6;

#pragma unroll
    for (int p = 0; p < 2; ++p) {          // feature halves (64 cols = 1 head)
      __syncthreads();
      if ((nw >> 6) == p) {
        if (part == 2) {
          // V half-tile as [64 d][136 t], 8B-packed writes (r -> t contiguous)
#pragma unroll
          for (int i = 0; i < MI; ++i)
#pragma unroll
            for (int j = 0; j < 4; ++j) {
              const int dh = j * 16 + l16;
              const int t0 = mw + i * 16 + quad * 4;
              uint2 pk;
              pk.x = pack2_bf16(acc[i][j][0] + bval[j], acc[i][j][1] + bval[j]);
              pk.y = pack2_bf16(acc[i][j][2] + bval[j], acc[i][j][3] + bval[j]);
              *(uint2*)&smem[dh * 136 + t0] = pk;
            }
        } else {
          // Q/K half-tile as [128 t][72 d] (stride-72: conflict-free writes)
          const float sc = (part == 0) ? QSCALE : 1.0f;
#pragma unroll
          for (int i = 0; i < MI; ++i)
#pragma unroll
            for (int j = 0; j < 4; ++j) {
              const int d = j * 16 + l16;
              const int t0 = mw + i * 16 + quad * 4;
#pragma unroll
              for (int r = 0; r < 4; ++r)
                smem[(t0 + r) * 72 + d] =
                    __float2bfloat16((acc[i][j][r] + bval[j]) * sc);
            }
        }
      }
      __syncthreads();
      const size_t bh = (size_t)(b * 16 + h0 + p);
      if (part == 2) {
        // store with per-64-tile chunk swizzle: chunk ^= (d & 7)
#pragma unroll
        for (int it = 0; it < 4; ++it) {
          const int dl = (tid >> 4) + it * 16;
          const int t8 = (tid & 15) * 8;
          const int t8s = (t8 & 64) | ((t8 ^ ((dl & 7) << 3)) & 63);
          short8 v = *(const short8*)&smem[dl * 136 + t8];
          *(short8*)&Vt[(bh * 64 + dl) * 2048 + tloc + t8s] = v;
        }
      } else {
        bf16* dst = (part == 0) ? Qd : Kd;
#pragma unroll
        for (int it = 0; it < 4; ++it) {
          const int row = (tid >> 3) + it * 32;
          const int col8 = (tid & 7) * 8;
          // K gets the 16B-chunk XOR swizzle; Q stays linear
          const int c8 = (part == 1) ? (col8 ^ ((row & 7) << 3)) : col8;
          short8 v = *(const short8*)&smem[row * 72 + col8];
          *(short8*)&dst[(bh * 2048 + tloc + row) * 64 + c8] = v;
        }
      }
    }
  } else {
#pragma unroll
    for (int j = 0; j < 4; ++j) {
      const int ncol = n_blk + nw + j * 16 + l16;
      const float bval = bias[ncol];
#pragma unroll
      for (int i = 0; i < MI; ++i) {
        const int mrow0 = m_blk + mw + i * 16 + quad * 4;
#pragma unroll
        for (int r = 0; r < 4; ++r)
          outp[(size_t)(mrow0 + r) * Nn + ncol] = acc[i][j][r] + bval;
      }
    }
  }
}

// ---------------- flash attention: Qtile=64, KVtile=64, quadrant split -------
// R8 kernel (best measured, 57.9 us) -- UNCHANGED this round (control).
// Async global_load_lds staging of pre-swizzled K/V; P in registers via
// pi-permuted K=32 PV; ones-MFMA row-sums; one DMA barrier per iteration.
__global__ __launch_bounds__(256, 4)
void attn_kernel(const bf16* __restrict__ Qg, const bf16* __restrict__ Kg,
                 const bf16* __restrict__ Vt, bf16* __restrict__ yg) {
  // [0,16384): Ks[2][64][64]; [16384,32768): Vts[2][64][64].
  // Epilogue reuse: red = 16 KiB partials at 0; sred = 256 B at 16384.
  __shared__ __align__(16) char pool[32768];
  bf16* KsB = (bf16*)pool;
  bf16* VtsB = (bf16*)(pool + 16384);

  const int tid = threadIdx.x;
  const int wave = tid >> 6, lane = tid & 63;
  const int quad = lane >> 4, l16 = lane & 15;
  const int qh = wave & 1, kvh = wave >> 1;

  // XCD-chunked swizzle (nwg=1024, bijective): XCD k gets heads [4k,4k+4)
  const int bx0 = blockIdx.x;
  const int bx = ((bx0 & 7) << 7) | (bx0 >> 3);
  const int qt = bx & 31;                // 32 q-tiles of 64
  const int bh = bx >> 5;                // b*16 + h

  const bf16* Qb = Qg + ((size_t)bh * 2048 + qt * 64) * 64;
  const bf16* Kb = Kg + (size_t)bh * 2048 * 64;
  const bf16* Vtb = Vt + (size_t)bh * 64 * 2048;

  // Q fragments (linear layout, pre-scaled by QSCALE at gemm0)
  short8 qf[2][2];
#pragma unroll
  for (int qblk = 0; qblk < 2; ++qblk)
#pragma unroll
    for (int ks = 0; ks < 2; ++ks)
      qf[qblk][ks] = *(const short8*)(
          Qb + (size_t)(qh * 32 + qblk * 16 + l16) * 64 + ks * 32 + quad * 8);

  // async staging pointers: wave w issues instrs j=0,1 per tensor.
  const int sj = wave * 2;
  const bf16* kg = Kb + sj * 512 + lane * 8;                       // +kt*64+j*512
  const bf16* vg = Vtb + (size_t)(sj * 8 + (lane >> 3)) * 2048 +
                   (lane & 7) * 8;                                  // +kt+j*16384

  // fragment read offsets (XOR de-swizzle; conflict-free)
  int kfo[2][2];
#pragma unroll
  for (int kvblk = 0; kvblk < 2; ++kvblk)
#pragma unroll
    for (int ks = 0; ks < 2; ++ks)
      kfo[kvblk][ks] = (kvh * 32 + kvblk * 16 + l16) * 64 +
                       (((ks * 4 + quad) ^ (l16 & 7)) << 3);
  int vbo[4][2];
#pragma unroll
  for (int dblk = 0; dblk < 4; ++dblk) {
    const int d = dblk * 16 + l16;
#pragma unroll
    for (int kvblk = 0; kvblk < 2; ++kvblk) {
      const int ct = kvh * 4 + kvblk * 2 + (quad >> 1);  // logical t-chunk
      vbo[dblk][kvblk] = d * 64 + ((ct ^ (d & 7)) << 3) + (quad & 1) * 4;
    }
  }

  // preamble: DMA tile 0 -> buf0
#pragma unroll
  for (int j = 0; j < 2; ++j) {
    gload_lds16(kg + j * 512, KsB + sj * 512 + j * 512);
    gload_lds16(vg + (size_t)j * 16384, VtsB + sj * 512 + j * 512);
  }
  DMA_BARRIER();

  f32x4 yacc[2][4];
#pragma unroll
  for (int qblk = 0; qblk < 2; ++qblk)
#pragma unroll
    for (int dblk = 0; dblk < 4; ++dblk)
      yacc[qblk][dblk] = (f32x4){0.f, 0.f, 0.f, 0.f};
  f32x4 sum_acc[2];
  sum_acc[0] = (f32x4){0.f, 0.f, 0.f, 0.f};
  sum_acc[1] = (f32x4){0.f, 0.f, 0.f, 0.f};

  uint4 ones_u;
  ones_u.x = ones_u.y = ones_u.z = ones_u.w = 0x3F803F80u;  // bf16 1.0 x8
  const short8 ones8 = __builtin_bit_cast(short8, ones_u);

  for (int kt = 0; kt < 2048; kt += 64) {
    const int cur = (kt >> 6) & 1;

    // 1. issue DMA for tile kt+64 into the other buffer (hidden under compute)
    if (kt + 64 < 2048) {
      bf16* Kdst = KsB + (cur ^ 1) * 4096;
      bf16* Vdst = VtsB + (cur ^ 1) * 4096;
#pragma unroll
      for (int j = 0; j < 2; ++j) {
        gload_lds16(kg + (kt + 64) * 64 + j * 512, Kdst + sj * 512 + j * 512);
        gload_lds16(vg + kt + 64 + (size_t)j * 16384, Vdst + sj * 512 + j * 512);
      }
    }
    const bf16* KsC = KsB + cur * 4096;
    const bf16* VtsC = VtsB + cur * 4096;

    // 2. K fragments for this wave's kv-half
    short8 kf[2][2];
#pragma unroll
    for (int kvblk = 0; kvblk < 2; ++kvblk)
#pragma unroll
      for (int ks = 0; ks < 2; ++ks)
        kf[kvblk][ks] = *(const short8*)(KsC + kfo[kvblk][ks]);

    // 3. S^T + softmax -> pa8; row-sum via ones-MFMA (no VALU adds)
    short8 pa8[2];
#pragma unroll
    for (int qblk = 0; qblk < 2; ++qblk) {
      f32x4 s0 = (f32x4){0.f, 0.f, 0.f, 0.f};
      f32x4 s1 = (f32x4){0.f, 0.f, 0.f, 0.f};
      s0 = __builtin_amdgcn_mfma_f32_16x16x32_bf16(kf[0][0], qf[qblk][0], s0, 0, 0, 0);
      s0 = __builtin_amdgcn_mfma_f32_16x16x32_bf16(kf[0][1], qf[qblk][1], s0, 0, 0, 0);
      s1 = __builtin_amdgcn_mfma_f32_16x16x32_bf16(kf[1][0], qf[qblk][0], s1, 0, 0, 0);
      s1 = __builtin_amdgcn_mfma_f32_16x16x32_bf16(kf[1][1], qf[qblk][1], s1, 0, 0, 0);
      float p0 = fast_exp2(s0[0]), p1 = fast_exp2(s0[1]);
      float p2 = fast_exp2(s0[2]), p3 = fast_exp2(s0[3]);
      float p4 = fast_exp2(s1[0]), p5 = fast_exp2(s1[1]);
      float p6 = fast_exp2(s1[2]), p7 = fast_exp2(s1[3]);
      uint4 u;
      u.x = pack2_bf16(p0, p1);
      u.y = pack2_bf16(p2, p3);
      u.z = pack2_bf16(p4, p5);
      u.w = pack2_bf16(p6, p7);
      pa8[qblk] = __builtin_bit_cast(short8, u);
      sum_acc[qblk] = __builtin_amdgcn_mfma_f32_16x16x32_bf16(
          pa8[qblk], ones8, sum_acc[qblk], 0, 0, 0);
    }

    // 4. Y += P·V, K=32 MFMA with pi-permuted V fragments (two b64 each)
#pragma unroll
    for (int dblk = 0; dblk < 4; ++dblk) {
      uint2 lo = *(const uint2*)(VtsC + vbo[dblk][0]);
      uint2 hi = *(const uint2*)(VtsC + vbo[dblk][1]);
      uint4 u;
      u.x = lo.x; u.y = lo.y; u.z = hi.x; u.w = hi.y;
      short8 vb8 = __builtin_bit_cast(short8, u);
      yacc[0][dblk] = __builtin_amdgcn_mfma_f32_16x16x32_bf16(
          pa8[0], vb8, yacc[0][dblk], 0, 0, 0);
      yacc[1][dblk] = __builtin_amdgcn_mfma_f32_16x16x32_bf16(
          pa8[1], vb8, yacc[1][dblk], 0, 0, 0);
    }

    // 5. single barrier: DMA for kt+64 landed + this iter's LDS reads done
    DMA_BARRIER();
  }

  // ---- epilogue: reduce kv-halves across waves (sums ride in sum_acc) ----
  __syncthreads();   // all waves done with K/V LDS before scratch overwrites
  float* red = (float*)pool;                 // 16384 B Y-partials
  float* sred = (float*)(pool + 16384);      // 256 B sums
  if (kvh == 1) {
#pragma unroll
    for (int qblk = 0; qblk < 2; ++qblk) {
#pragma unroll
      for (int dblk = 0; dblk < 4; ++dblk) {
        const int f = (qh * 2 + qblk) * 4 + dblk;
        *(f32x4*)&red[(f * 64 + quad * 16 + l16) * 4] = yacc[qblk][dblk];
      }
      if (l16 == 0)
        *(f32x4*)&sred[(qh * 2 + qblk) * 16 + quad * 4] = sum_acc[qblk];
    }
  }
  __syncthreads();
  if (kvh == 0) {
    const int b = bh >> 4, h = bh & 15;
    const size_t rowbase = (size_t)b * 2048 + qt * 64;
#pragma unroll
    for (int qblk = 0; qblk < 2; ++qblk) {
      f32x4 sp = *(const f32x4*)&sred[(qh * 2 + qblk) * 16 + quad * 4];
#pragma unroll
      for (int dblk = 0; dblk < 4; ++dblk) {
        const int f = (qh * 2 + qblk) * 4 + dblk;
        f32x4 o = *(const f32x4*)&red[(f * 64 + quad * 16 + l16) * 4];
#pragma unroll
        for (int r = 0; r < 4; ++r) yacc[qblk][dblk][r] += o[r];
      }
#pragma unroll
      for (int r = 0; r < 4; ++r) {
        const float inv = 1.f / (sum_acc[qblk][r] + sp[r]);
        const int rr = qh * 32 + qblk * 16 + quad * 4 + r;
#pragma unroll
        for (int dblk = 0; dblk < 4; ++dblk)
          yg[(rowbase + rr) * 1024 + h * 64 + dblk * 16 + l16] =
              __float2bfloat16(yacc[qblk][dblk][r] * inv);
      }
    }
  }
}

// ---------------- launch ----------------
extern "C" void kernel_launch(void* const* d_in, const int* in_sizes, int n_in,
                              void* d_out, int out_size, void* d_ws, size_t ws_size,
                              hipStream_t stream) {
  const float* x = (const float*)d_in[0];      // [4096, 1024] fp32
  const float* Wqkv = (const float*)d_in[1];   // [1024, 3072] fp32
  const float* bqkv = (const float*)d_in[2];   // [3072] fp32
  const float* Wproj = (const float*)d_in[3];  // [1024, 1024] fp32
  const float* bproj = (const float*)d_in[4];  // [1024] fp32
  float* out = (float*)d_out;                  // [4096, 1024] fp32

  if (ws_size < (size_t)40 * 1024 * 1024) return;

  char* ws = (char*)d_ws;
  bf16* xb    = (bf16*)(ws + 0);             // [4096,1024] = 8 MiB
  bf16* yd    = (bf16*)(ws + 0);             // aliases xb (dead after gemm0)
  bf16* WtQkv = (bf16*)(ws + 8388608);       // [3072,1024] = 6 MiB
  bf16* WtP   = (bf16*)(ws + 14680064);      // [1024,1024] = 2 MiB
  bf16* Qd    = (bf16*)(ws + 16777216);      // [32,2048,64] = 8 MiB (pre-scaled)
  bf16* Kd    = (bf16*)(ws + 25165824);      // 8 MiB (chunk-swizzled rows)
  bf16* Vten  = (bf16*)(ws + 33554432);      // [32,64,2048] = 8 MiB (swizzled)

  prep_k<<<3072, 256, 0, stream>>>(x, xb, Wqkv, WtQkv, Wproj, WtP);
  gemm_bt<0, 128><<<dim3(24, 32), 256, 0, stream>>>(
      xb, WtQkv, bqkv, nullptr, Qd, Kd, Vten, 4096, 3072, 1024);
  attn_kernel<<<dim3(1024), 256, 0, stream>>>(Qd, Kd, Vten, yd);
  gemm_bt<1, 64><<<dim3(8, 64), 256, 0, stream>>>(
      yd, WtP, bproj, out, nullptr, nullptr, nullptr, 4096, 1024, 1024);
}

// Round 10
// 185.608 us; speedup vs baseline: 1.0079x; 1.0079x over previous
//
#include <hip/hip_runtime.h>
#include <hip/hip_bf16.h>
#include <stdint.h>

typedef __hip_bfloat16 bf16;
typedef __attribute__((ext_vector_type(8))) short short8;   // 8 bf16
typedef __attribute__((ext_vector_type(4))) float f32x4;

#define QSCALE 0.18033688011f   // 0.125 * log2(e), folded into Q at gemm0

// ---- 1-instr helpers ----
__device__ __forceinline__ float fast_exp2(float x) {
#if __has_builtin(__builtin_amdgcn_exp2f)
  return __builtin_amdgcn_exp2f(x);
#else
  return exp2f(x);
#endif
}

__device__ __forceinline__ uint32_t pack2_bf16(float a, float b) {
#if __has_builtin(__builtin_amdgcn_cvt_pk_bf16_f32)
  typedef __attribute__((ext_vector_type(2))) __bf16 bf16x2;
  bf16x2 v = __builtin_amdgcn_cvt_pk_bf16_f32(a, b);
  return __builtin_bit_cast(uint32_t, v);
#else
  uint32_t ua = __builtin_bit_cast(uint32_t, a);
  uint32_t ub = __builtin_bit_cast(uint32_t, b);
  ua += 0x7FFF + ((ua >> 16) & 1);   // RNE
  ub += 0x7FFF + ((ub >> 16) & 1);
  return (ua >> 16) | (ub & 0xFFFF0000u);
#endif
}

// async global->LDS, 16B per lane: g is the PER-LANE global pointer,
// l is the WAVE-UNIFORM LDS base (lane lands at l + lane*16B).
__device__ __forceinline__ void gload_lds16(const bf16* g, bf16* l) {
#if __has_builtin(__builtin_amdgcn_global_load_lds)
  __builtin_amdgcn_global_load_lds(
      (const __attribute__((address_space(1))) void*)(uintptr_t)g,
      (__attribute__((address_space(3))) void*)(uint32_t)(uintptr_t)l,
      16, 0, 0);
#else
  int lane = threadIdx.x & 63;
  *(short8*)(l + lane * 8) = *(const short8*)(g + lane * 8);
#endif
}

// T4 counted-vmcnt barriers: each wave verifies its OWN older DMAs are done
// BEFORE the barrier -> after the barrier the collective tile has landed,
// while the 4 (or 3) just-issued prefetch DMAs stay in flight. Never drain
// vmcnt to 0 in a main loop (m218: counted-vs-drain0 = +38-73%).
#define VM4_BARRIER() \
  asm volatile("s_waitcnt vmcnt(4)\n\ts_barrier" ::: "memory")
#define VM3_BARRIER() \
  asm volatile("s_waitcnt vmcnt(3)\n\ts_barrier" ::: "memory")
// WAR-protect barrier: all waves done reading before next overwrite.
#define LDSR_BARRIER() \
  asm volatile("s_waitcnt lgkmcnt(0)\n\ts_barrier" ::: "memory")
// full drain (epilogue entry: dummy prefetches may still target the pool)
#define DMA_BARRIER() \
  asm volatile("s_waitcnt vmcnt(0) lgkmcnt(0)\n\ts_barrier" ::: "memory")

// ---- fp32->bf16 transpose tile body (64x64) ----
__device__ __forceinline__ void transpose_tile(const float* __restrict__ in,
                                               bf16* __restrict__ out,
                                               int R, int C, int bx, int by,
                                               bf16 (*t)[72]) {
  const int r0 = by * 64, c0 = bx * 64;
  const int rr = threadIdx.x >> 3, cc = (threadIdx.x & 7) * 8;
#pragma unroll
  for (int rep = 0; rep < 2; ++rep) {
    int y = rr + rep * 32;
    const float* p = in + (size_t)(r0 + y) * C + c0 + cc;
    f32x4 v0 = *(const f32x4*)p;
    f32x4 v1 = *(const f32x4*)(p + 4);
#pragma unroll
    for (int j = 0; j < 4; ++j) {
      t[cc + j][y] = __float2bfloat16(v0[j]);
      t[cc + 4 + j][y] = __float2bfloat16(v1[j]);
    }
  }
  __syncthreads();
#pragma unroll
  for (int rep = 0; rep < 2; ++rep) {
    int y = rr + rep * 32;
    short8 v = *(const short8*)&t[y][cc];
    *(short8*)(out + (size_t)(c0 + y) * R + r0 + cc) = v;
  }
}

// ---- fused prep: x->bf16 (blocks 0..2047), Wqkv^T (2048..2815),
//      Wproj^T (2816..3071) ----
__global__ __launch_bounds__(256)
void prep_k(const float* __restrict__ x, bf16* __restrict__ xb,
            const float* __restrict__ Wqkv, bf16* __restrict__ WtQkv,
            const float* __restrict__ Wproj, bf16* __restrict__ WtP) {
  __shared__ __align__(16) bf16 t[64][72];
  const int bid = blockIdx.x;
  if (bid < 2048) {
    int i = (bid * 256 + threadIdx.x) * 8;
    f32x4 v0 = *(const f32x4*)(x + i);
    f32x4 v1 = *(const f32x4*)(x + i + 4);
    short8 r;
    bf16* rb = (bf16*)&r;
#pragma unroll
    for (int j = 0; j < 4; ++j) {
      rb[j] = __float2bfloat16(v0[j]);
      rb[4 + j] = __float2bfloat16(v1[j]);
    }
    *(short8*)(xb + i) = r;
  } else if (bid < 2048 + 768) {
    int b = bid - 2048;
    transpose_tile(Wqkv, WtQkv, 1024, 3072, b % 48, b / 48, t);
  } else {
    int b = bid - 2816;
    transpose_tile(Wproj, WtP, 1024, 1024, b % 16, b / 16, t);
  }
}

// ---------------- GEMM: C[m][n] = A[m,:]·Bt[n,:] + bias[n] -------------------
// Double-buffered async staging with COUNTED vmcnt (T4): per iteration,
// issue next-tile DMA -> vmcnt(N)+barrier (tile kt landed, prefetch still
// in flight) -> frag reads + MFMA -> lgkmcnt+barrier (WAR). The last
// iteration issues a clamped dummy prefetch so the count stays uniform;
// DMA_BARRIER before the epilogue drains it before LDS reuse.
// MODE 0 (TM=128): LDS-transposed coalesced epilogue -> Q (xQSCALE) as
//   [bh][t][64] (linear), K as [bh][t][64] with 16B-chunk XOR-swizzle
//   (chunk ^= row&7), V^T as [bh][64][t] with per-64-tile chunk XOR-swizzle
//   (chunk ^= d&7) -- lets attn stage K/V linearly via global_load_lds and
//   read fragments conflict-free.
// MODE 1 (TM=64): fp32 out row-major [M,Nn].
// Grid XCD-chunk swizzled (nwg % 8 == 0 -> bijective).
template <int MODE, int TM>
__global__ __launch_bounds__(256, (TM == 128) ? 3 : 2)
void gemm_bt(const bf16* __restrict__ A, const bf16* __restrict__ Bt,
             const float* __restrict__ bias, float* __restrict__ outp,
             bf16* __restrict__ Qd, bf16* __restrict__ Kd, bf16* __restrict__ Vt,
             int M, int Nn, int K) {
  constexpr int MI = TM / 32;
  constexpr int BUFE = TM * 32 + 4096;   // elements per staging buffer
  // 2 staging buffers; MODE-0 epilogue (<=9216 el) reuses the pool
  __shared__ __align__(16) bf16 smem[2 * BUFE];

  const int tid = threadIdx.x;
  const int wave = tid >> 6, lane = tid & 63;
  const int quad = lane >> 4, l16 = lane & 15;
  const int mw = (wave >> 1) * (TM / 2), nw = (wave & 1) * 64;

  // XCD-chunked swizzle of the linearized block id
  const int nwg = gridDim.x * gridDim.y;
  const int ord = blockIdx.y * gridDim.x + blockIdx.x;
  const int wg = (ord & 7) * (nwg >> 3) + (ord >> 3);
  const int m_blk = (wg / gridDim.x) * TM, n_blk = (wg % gridDim.x) * 128;

  f32x4 acc[MI][4];
#pragma unroll
  for (int i = 0; i < MI; ++i)
#pragma unroll
    for (int j = 0; j < 4; ++j) acc[i][j] = (f32x4){0.f, 0.f, 0.f, 0.f};

  const int rowA = lane >> 2, colA = (lane & 3) * 8;
  const int chunkB = wave * 2;
  const bf16* gB = Bt + (size_t)(n_blk + chunkB * 16 + rowA) * K + colA;
  const int chunkA = (TM == 128) ? wave * 2 : wave;
  const bf16* gA = A + (size_t)(m_blk + chunkA * 16 + rowA) * K + colA;

  // in-buffer LDS offsets (wave-uniform bases for the DMA)
  const int oA0 = chunkA * 512;
  const int oA1 = (chunkA + 1) * 512;             // unused for TM=64
  const int oB0 = TM * 32 + chunkB * 512;
  const int oB1 = TM * 32 + (chunkB + 1) * 512;

  // prologue: issue DMA tile 0 -> buffer 0 (no wait; loop's barrier covers)
  gload_lds16(gA, smem + oA0);
  if (TM == 128) gload_lds16(gA + 16 * K, smem + oA1);
  gload_lds16(gB, smem + oB0);
  gload_lds16(gB + 16 * K, smem + oB1);

  for (int kt = 0; kt < K; kt += 32) {
    const int cur = (kt >> 5) & 1;
    bf16* bufc = smem + cur * BUFE;

    // 1. issue DMA for the next tile (clamped dummy on the last iteration)
    {
      const int kn = (kt + 32 < K) ? (kt + 32) : (K - 32);
      bf16* bufn = smem + (cur ^ 1) * BUFE;
      gload_lds16(gA + kn, bufn + oA0);
      if (TM == 128) gload_lds16(gA + 16 * K + kn, bufn + oA1);
      gload_lds16(gB + kn, bufn + oB0);
      gload_lds16(gB + 16 * K + kn, bufn + oB1);
    }

    // 2. counted wait + barrier: tile kt landed block-wide; prefetch rides on
    if constexpr (TM == 128) VM4_BARRIER(); else VM3_BARRIER();

    // 3. compute tile kt
    short8 af[MI], bfv[4];
#pragma unroll
    for (int i = 0; i < MI; ++i)
      af[i] = *(const short8*)&bufc[(mw + i * 16 + l16) * 32 + quad * 8];
#pragma unroll
    for (int j = 0; j < 4; ++j)
      bfv[j] = *(const short8*)&bufc[TM * 32 + (nw + j * 16 + l16) * 32 + quad * 8];
#pragma unroll
    for (int i = 0; i < MI; ++i)
#pragma unroll
      for (int j = 0; j < 4; ++j)
        acc[i][j] = __builtin_amdgcn_mfma_f32_16x16x32_bf16(af[i], bfv[j],
                                                            acc[i][j], 0, 0, 0);

    // 4. WAR barrier: reads of bufc done before next iter overwrites it
    LDSR_BARRIER();
  }

  // drain dummy prefetch before the epilogue reuses / exits
  DMA_BARRIER();

  if (MODE == 0) {
    // per-j bias for this wave's columns
    float bval[4];
#pragma unroll
    for (int j = 0; j < 4; ++j) bval[j] = bias[n_blk + nw + j * 16 + l16];

    const int part = n_blk >> 10;          // 0:q 1:k 2:v (block-uniform)
    const int b = m_blk >> 11;
    const int tloc = m_blk & 2047;
    const int h0 = (n_blk & 1023) >> 6;

#pragma unroll
    for (int p = 0; p < 2; ++p) {          // feature halves (64 cols = 1 head)
      __syncthreads();
      if ((nw >> 6) == p) {
        if (part == 2) {
          // V half-tile as [64 d][136 t], 8B-packed writes (r -> t contiguous)
#pragma unroll
          for (int i = 0; i < MI; ++i)
#pragma unroll
            for (int j = 0; j < 4; ++j) {
              const int dh = j * 16 + l16;
              const int t0 = mw + i * 16 + quad * 4;
              uint2 pk;
              pk.x = pack2_bf16(acc[i][j][0] + bval[j], acc[i][j][1] + bval[j]);
              pk.y = pack2_bf16(acc[i][j][2] + bval[j], acc[i][j][3] + bval[j]);
              *(uint2*)&smem[dh * 136 + t0] = pk;
            }
        } else {
          // Q/K half-tile as [128 t][72 d] (stride-72: conflict-free writes)
          const float sc = (part == 0) ? QSCALE : 1.0f;
#pragma unroll
          for (int i = 0; i < MI; ++i)
#pragma unroll
            for (int j = 0; j < 4; ++j) {
              const int d = j * 16 + l16;
              const int t0 = mw + i * 16 + quad * 4;
#pragma unroll
              for (int r = 0; r < 4; ++r)
                smem[(t0 + r) * 72 + d] =
                    __float2bfloat16((acc[i][j][r] + bval[j]) * sc);
            }
        }
      }
      __syncthreads();
      const size_t bh = (size_t)(b * 16 + h0 + p);
      if (part == 2) {
        // store with per-64-tile chunk swizzle: chunk ^= (d & 7)
#pragma unroll
        for (int it = 0; it < 4; ++it) {
          const int dl = (tid >> 4) + it * 16;
          const int t8 = (tid & 15) * 8;
          const int t8s = (t8 & 64) | ((t8 ^ ((dl & 7) << 3)) & 63);
          short8 v = *(const short8*)&smem[dl * 136 + t8];
          *(short8*)&Vt[(bh * 64 + dl) * 2048 + tloc + t8s] = v;
        }
      } else {
        bf16* dst = (part == 0) ? Qd : Kd;
#pragma unroll
        for (int it = 0; it < 4; ++it) {
          const int row = (tid >> 3) + it * 32;
          const int col8 = (tid & 7) * 8;
          // K gets the 16B-chunk XOR swizzle; Q stays linear
          const int c8 = (part == 1) ? (col8 ^ ((row & 7) << 3)) : col8;
          short8 v = *(const short8*)&smem[row * 72 + col8];
          *(short8*)&dst[(bh * 2048 + tloc + row) * 64 + c8] = v;
        }
      }
    }
  } else {
#pragma unroll
    for (int j = 0; j < 4; ++j) {
      const int ncol = n_blk + nw + j * 16 + l16;
      const float bval = bias[ncol];
#pragma unroll
      for (int i = 0; i < MI; ++i) {
        const int mrow0 = m_blk + mw + i * 16 + quad * 4;
#pragma unroll
        for (int r = 0; r < 4; ++r)
          outp[(size_t)(mrow0 + r) * Nn + ncol] = acc[i][j][r] + bval;
      }
    }
  }
}

// ---------------- flash attention: Qtile=64, KVtile=64, quadrant split -------
// R8 structure with COUNTED vmcnt (T4): per iteration, issue next-tile DMA ->
// vmcnt(4)+barrier (tile kt landed block-wide; the 4 just-issued prefetch
// DMAs stay in flight across the barrier) -> frag reads, S^T, softmax, PV ->
// lgkmcnt+barrier (WAR before next overwrite). Last iteration issues a
// clamped dummy prefetch for a uniform count; DMA_BARRIER drains it before
// the epilogue reuses the pool. P in registers via pi-permuted K=32 PV;
// ones-MFMA row-sums; pre-swizzled K/V; 32768 B LDS -> 4 blocks/CU.
__global__ __launch_bounds__(256, 4)
void attn_kernel(const bf16* __restrict__ Qg, const bf16* __restrict__ Kg,
                 const bf16* __restrict__ Vt, bf16* __restrict__ yg) {
  // [0,16384): Ks[2][64][64]; [16384,32768): Vts[2][64][64].
  // Epilogue reuse: red = 16 KiB partials at 0; sred = 256 B at 16384.
  __shared__ __align__(16) char pool[32768];
  bf16* KsB = (bf16*)pool;
  bf16* VtsB = (bf16*)(pool + 16384);

  const int tid = threadIdx.x;
  const int wave = tid >> 6, lane = tid & 63;
  const int quad = lane >> 4, l16 = lane & 15;
  const int qh = wave & 1, kvh = wave >> 1;

  // XCD-chunked swizzle (nwg=1024, bijective): XCD k gets heads [4k,4k+4)
  const int bx0 = blockIdx.x;
  const int bx = ((bx0 & 7) << 7) | (bx0 >> 3);
  const int qt = bx & 31;                // 32 q-tiles of 64
  const int bh = bx >> 5;                // b*16 + h

  const bf16* Qb = Qg + ((size_t)bh * 2048 + qt * 64) * 64;
  const bf16* Kb = Kg + (size_t)bh * 2048 * 64;
  const bf16* Vtb = Vt + (size_t)bh * 64 * 2048;

  // Q fragments (linear layout, pre-scaled by QSCALE at gemm0)
  short8 qf[2][2];
#pragma unroll
  for (int qblk = 0; qblk < 2; ++qblk)
#pragma unroll
    for (int ks = 0; ks < 2; ++ks)
      qf[qblk][ks] = *(const short8*)(
          Qb + (size_t)(qh * 32 + qblk * 16 + l16) * 64 + ks * 32 + quad * 8);

  // async staging pointers: wave w issues instrs j=0,1 per tensor.
  const int sj = wave * 2;
  const bf16* kg = Kb + sj * 512 + lane * 8;                       // +kt*64+j*512
  const bf16* vg = Vtb + (size_t)(sj * 8 + (lane >> 3)) * 2048 +
                   (lane & 7) * 8;                                  // +kt+j*16384

  // fragment read offsets (XOR de-swizzle; conflict-free)
  int kfo[2][2];
#pragma unroll
  for (int kvblk = 0; kvblk < 2; ++kvblk)
#pragma unroll
    for (int ks = 0; ks < 2; ++ks)
      kfo[kvblk][ks] = (kvh * 32 + kvblk * 16 + l16) * 64 +
                       (((ks * 4 + quad) ^ (l16 & 7)) << 3);
  int vbo[4][2];
#pragma unroll
  for (int dblk = 0; dblk < 4; ++dblk) {
    const int d = dblk * 16 + l16;
#pragma unroll
    for (int kvblk = 0; kvblk < 2; ++kvblk) {
      const int ct = kvh * 4 + kvblk * 2 + (quad >> 1);  // logical t-chunk
      vbo[dblk][kvblk] = d * 64 + ((ct ^ (d & 7)) << 3) + (quad & 1) * 4;
    }
  }

  // preamble: issue DMA tile 0 -> buf0 (no wait; loop's barrier covers)
#pragma unroll
  for (int j = 0; j < 2; ++j) {
    gload_lds16(kg + j * 512, KsB + sj * 512 + j * 512);
    gload_lds16(vg + (size_t)j * 16384, VtsB + sj * 512 + j * 512);
  }

  f32x4 yacc[2][4];
#pragma unroll
  for (int qblk = 0; qblk < 2; ++qblk)
#pragma unroll
    for (int dblk = 0; dblk < 4; ++dblk)
      yacc[qblk][dblk] = (f32x4){0.f, 0.f, 0.f, 0.f};
  f32x4 sum_acc[2];
  sum_acc[0] = (f32x4){0.f, 0.f, 0.f, 0.f};
  sum_acc[1] = (f32x4){0.f, 0.f, 0.f, 0.f};

  uint4 ones_u;
  ones_u.x = ones_u.y = ones_u.z = ones_u.w = 0x3F803F80u;  // bf16 1.0 x8
  const short8 ones8 = __builtin_bit_cast(short8, ones_u);

  for (int kt = 0; kt < 2048; kt += 64) {
    const int cur = (kt >> 6) & 1;

    // 1. issue DMA for the next tile (clamped dummy on the last iteration)
    {
      const int kn = (kt + 64 < 2048) ? (kt + 64) : (2048 - 64);
      bf16* Kdst = KsB + (cur ^ 1) * 4096;
      bf16* Vdst = VtsB + (cur ^ 1) * 4096;
#pragma unroll
      for (int j = 0; j < 2; ++j) {
        gload_lds16(kg + kn * 64 + j * 512, Kdst + sj * 512 + j * 512);
        gload_lds16(vg + kn + (size_t)j * 16384, Vdst + sj * 512 + j * 512);
      }
    }

    // 2. counted wait + barrier: tile kt landed block-wide; prefetch rides on
    VM4_BARRIER();

    const bf16* KsC = KsB + cur * 4096;
    const bf16* VtsC = VtsB + cur * 4096;

    // 3. K fragments for this wave's kv-half
    short8 kf[2][2];
#pragma unroll
    for (int kvblk = 0; kvblk < 2; ++kvblk)
#pragma unroll
      for (int ks = 0; ks < 2; ++ks)
        kf[kvblk][ks] = *(const short8*)(KsC + kfo[kvblk][ks]);

    // 4. S^T + softmax -> pa8; row-sum via ones-MFMA (no VALU adds)
    short8 pa8[2];
#pragma unroll
    for (int qblk = 0; qblk < 2; ++qblk) {
      f32x4 s0 = (f32x4){0.f, 0.f, 0.f, 0.f};
      f32x4 s1 = (f32x4){0.f, 0.f, 0.f, 0.f};
      s0 = __builtin_amdgcn_mfma_f32_16x16x32_bf16(kf[0][0], qf[qblk][0], s0, 0, 0, 0);
      s0 = __builtin_amdgcn_mfma_f32_16x16x32_bf16(kf[0][1], qf[qblk][1], s0, 0, 0, 0);
      s1 = __builtin_amdgcn_mfma_f32_16x16x32_bf16(kf[1][0], qf[qblk][0], s1, 0, 0, 0);
      s1 = __builtin_amdgcn_mfma_f32_16x16x32_bf16(kf[1][1], qf[qblk][1], s1, 0, 0, 0);
      float p0 = fast_exp2(s0[0]), p1 = fast_exp2(s0[1]);
      float p2 = fast_exp2(s0[2]), p3 = fast_exp2(s0[3]);
      float p4 = fast_exp2(s1[0]), p5 = fast_exp2(s1[1]);
      float p6 = fast_exp2(s1[2]), p7 = fast_exp2(s1[3]);
      uint4 u;
      u.x = pack2_bf16(p0, p1);
      u.y = pack2_bf16(p2, p3);
      u.z = pack2_bf16(p4, p5);
      u.w = pack2_bf16(p6, p7);
      pa8[qblk] = __builtin_bit_cast(short8, u);
      sum_acc[qblk] = __builtin_amdgcn_mfma_f32_16x16x32_bf16(
          pa8[qblk], ones8, sum_acc[qblk], 0, 0, 0);
    }

    // 5. Y += P·V, K=32 MFMA with pi-permuted V fragments (two b64 each)
#pragma unroll
    for (int dblk = 0; dblk < 4; ++dblk) {
      uint2 lo = *(const uint2*)(VtsC + vbo[dblk][0]);
      uint2 hi = *(const uint2*)(VtsC + vbo[dblk][1]);
      uint4 u;
      u.x = lo.x; u.y = lo.y; u.z = hi.x; u.w = hi.y;
      short8 vb8 = __builtin_bit_cast(short8, u);
      yacc[0][dblk] = __builtin_amdgcn_mfma_f32_16x16x32_bf16(
          pa8[0], vb8, yacc[0][dblk], 0, 0, 0);
      yacc[1][dblk] = __builtin_amdgcn_mfma_f32_16x16x32_bf16(
          pa8[1], vb8, yacc[1][dblk], 0, 0, 0);
    }

    // 6. WAR barrier: reads of buf[cur] done before next iter overwrites it
    LDSR_BARRIER();
  }

  // ---- epilogue: drain dummy prefetch, then reduce kv-halves ----
  DMA_BARRIER();
  float* red = (float*)pool;                 // 16384 B Y-partials
  float* sred = (float*)(pool + 16384);      // 256 B sums
  if (kvh == 1) {
#pragma unroll
    for (int qblk = 0; qblk < 2; ++qblk) {
#pragma unroll
      for (int dblk = 0; dblk < 4; ++dblk) {
        const int f = (qh * 2 + qblk) * 4 + dblk;
        *(f32x4*)&red[(f * 64 + quad * 16 + l16) * 4] = yacc[qblk][dblk];
      }
      if (l16 == 0)
        *(f32x4*)&sred[(qh * 2 + qblk) * 16 + quad * 4] = sum_acc[qblk];
    }
  }
  __syncthreads();
  if (kvh == 0) {
    const int b = bh >> 4, h = bh & 15;
    const size_t rowbase = (size_t)b * 2048 + qt * 64;
#pragma unroll
    for (int qblk = 0; qblk < 2; ++qblk) {
      f32x4 sp = *(const f32x4*)&sred[(qh * 2 + qblk) * 16 + quad * 4];
#pragma unroll
      for (int dblk = 0; dblk < 4; ++dblk) {
        const int f = (qh * 2 + qblk) * 4 + dblk;
        f32x4 o = *(const f32x4*)&red[(f * 64 + quad * 16 + l16) * 4];
#pragma unroll
        for (int r = 0; r < 4; ++r) yacc[qblk][dblk][r] += o[r];
      }
#pragma unroll
      for (int r = 0; r < 4; ++r) {
        const float inv = 1.f / (sum_acc[qblk][r] + sp[r]);
        const int rr = qh * 32 + qblk * 16 + quad * 4 + r;
#pragma unroll
        for (int dblk = 0; dblk < 4; ++dblk)
          yg[(rowbase + rr) * 1024 + h * 64 + dblk * 16 + l16] =
              __float2bfloat16(yacc[qblk][dblk][r] * inv);
      }
    }
  }
}

// ---------------- launch ----------------
extern "C" void kernel_launch(void* const* d_in, const int* in_sizes, int n_in,
                              void* d_out, int out_size, void* d_ws, size_t ws_size,
                              hipStream_t stream) {
  const float* x = (const float*)d_in[0];      // [4096, 1024] fp32
  const float* Wqkv = (const float*)d_in[1];   // [1024, 3072] fp32
  const float* bqkv = (const float*)d_in[2];   // [3072] fp32
  const float* Wproj = (const float*)d_in[3];  // [1024, 1024] fp32
  const float* bproj = (const float*)d_in[4];  // [1024] fp32
  float* out = (float*)d_out;                  // [4096, 1024] fp32

  if (ws_size < (size_t)40 * 1024 * 1024) return;

  char* ws = (char*)d_ws;
  bf16* xb    = (bf16*)(ws + 0);             // [4096,1024] = 8 MiB
  bf16* yd    = (bf16*)(ws + 0);             // aliases xb (dead after gemm0)
  bf16* WtQkv = (bf16*)(ws + 8388608);       // [3072,1024] = 6 MiB
  bf16* WtP   = (bf16*)(ws + 14680064);      // [1024,1024] = 2 MiB
  bf16* Qd    = (bf16*)(ws + 16777216);      // [32,2048,64] = 8 MiB (pre-scaled)
  bf16* Kd    = (bf16*)(ws + 25165824);      // 8 MiB (chunk-swizzled rows)
  bf16* Vten  = (bf16*)(ws + 33554432);      // [32,64,2048] = 8 MiB (swizzled)

  prep_k<<<3072, 256, 0, stream>>>(x, xb, Wqkv, WtQkv, Wproj, WtP);
  gemm_bt<0, 128><<<dim3(24, 32), 256, 0, stream>>>(
      xb, WtQkv, bqkv, nullptr, Qd, Kd, Vten, 4096, 3072, 1024);
  attn_kernel<<<dim3(1024), 256, 0, stream>>>(Qd, Kd, Vten, yd);
  gemm_bt<1, 64><<<dim3(8, 64), 256, 0, stream>>>(
      yd, WtP, bproj, out, nullptr, nullptr, nullptr, 4096, 1024, 1024);
}

// Round 11
// 180.544 us; speedup vs baseline: 1.0362x; 1.0280x over previous
//
#include <hip/hip_runtime.h>
#include <hip/hip_bf16.h>
#include <stdint.h>

typedef __hip_bfloat16 bf16;
typedef __attribute__((ext_vector_type(8))) short short8;   // 8 bf16
typedef __attribute__((ext_vector_type(4))) float f32x4;

#define QSCALE 0.18033688011f   // 0.125 * log2(e), folded into Q at gemm0

// ---- 1-instr helpers ----
__device__ __forceinline__ float fast_exp2(float x) {
#if __has_builtin(__builtin_amdgcn_exp2f)
  return __builtin_amdgcn_exp2f(x);
#else
  return exp2f(x);
#endif
}

__device__ __forceinline__ uint32_t pack2_bf16(float a, float b) {
#if __has_builtin(__builtin_amdgcn_cvt_pk_bf16_f32)
  typedef __attribute__((ext_vector_type(2))) __bf16 bf16x2;
  bf16x2 v = __builtin_amdgcn_cvt_pk_bf16_f32(a, b);
  return __builtin_bit_cast(uint32_t, v);
#else
  uint32_t ua = __builtin_bit_cast(uint32_t, a);
  uint32_t ub = __builtin_bit_cast(uint32_t, b);
  ua += 0x7FFF + ((ua >> 16) & 1);   // RNE
  ub += 0x7FFF + ((ub >> 16) & 1);
  return (ua >> 16) | (ub & 0xFFFF0000u);
#endif
}

// async global->LDS, 16B per lane: g is the PER-LANE global pointer,
// l is the WAVE-UNIFORM LDS base (lane lands at l + lane*16B).
__device__ __forceinline__ void gload_lds16(const bf16* g, bf16* l) {
#if __has_builtin(__builtin_amdgcn_global_load_lds)
  __builtin_amdgcn_global_load_lds(
      (const __attribute__((address_space(1))) void*)(uintptr_t)g,
      (__attribute__((address_space(3))) void*)(uint32_t)(uintptr_t)l,
      16, 0, 0);
#else
  int lane = threadIdx.x & 63;
  *(short8*)(l + lane * 8) = *(const short8*)(g + lane * 8);
#endif
}

// T4 counted-vmcnt barriers: each wave verifies its OWN older DMAs are done
// BEFORE the barrier -> after the barrier the collective tile has landed,
// while the just-issued prefetch DMAs stay in flight.
#define VM4_BARRIER() \
  asm volatile("s_waitcnt vmcnt(4)\n\ts_barrier" ::: "memory")
#define VM3_BARRIER() \
  asm volatile("s_waitcnt vmcnt(3)\n\ts_barrier" ::: "memory")
// WAR-protect barrier (attn 2-buffer loop): reads done before next overwrite.
#define LDSR_BARRIER() \
  asm volatile("s_waitcnt lgkmcnt(0)\n\ts_barrier" ::: "memory")
// full drain (epilogue entry: dummy prefetches may still target the pool)
#define DMA_BARRIER() \
  asm volatile("s_waitcnt vmcnt(0) lgkmcnt(0)\n\ts_barrier" ::: "memory")

// ---- fp32->bf16 transpose tile body (64x64) ----
__device__ __forceinline__ void transpose_tile(const float* __restrict__ in,
                                               bf16* __restrict__ out,
                                               int R, int C, int bx, int by,
                                               bf16 (*t)[72]) {
  const int r0 = by * 64, c0 = bx * 64;
  const int rr = threadIdx.x >> 3, cc = (threadIdx.x & 7) * 8;
#pragma unroll
  for (int rep = 0; rep < 2; ++rep) {
    int y = rr + rep * 32;
    const float* p = in + (size_t)(r0 + y) * C + c0 + cc;
    f32x4 v0 = *(const f32x4*)p;
    f32x4 v1 = *(const f32x4*)(p + 4);
#pragma unroll
    for (int j = 0; j < 4; ++j) {
      t[cc + j][y] = __float2bfloat16(v0[j]);
      t[cc + 4 + j][y] = __float2bfloat16(v1[j]);
    }
  }
  __syncthreads();
#pragma unroll
  for (int rep = 0; rep < 2; ++rep) {
    int y = rr + rep * 32;
    short8 v = *(const short8*)&t[y][cc];
    *(short8*)(out + (size_t)(c0 + y) * R + r0 + cc) = v;
  }
}

// ---- fused prep: x->bf16 (blocks 0..2047), Wqkv^T (2048..2815),
//      Wproj^T (2816..3071) ----
__global__ __launch_bounds__(256)
void prep_k(const float* __restrict__ x, bf16* __restrict__ xb,
            const float* __restrict__ Wqkv, bf16* __restrict__ WtQkv,
            const float* __restrict__ Wproj, bf16* __restrict__ WtP) {
  __shared__ __align__(16) bf16 t[64][72];
  const int bid = blockIdx.x;
  if (bid < 2048) {
    int i = (bid * 256 + threadIdx.x) * 8;
    f32x4 v0 = *(const f32x4*)(x + i);
    f32x4 v1 = *(const f32x4*)(x + i + 4);
    short8 r;
    bf16* rb = (bf16*)&r;
#pragma unroll
    for (int j = 0; j < 4; ++j) {
      rb[j] = __float2bfloat16(v0[j]);
      rb[4 + j] = __float2bfloat16(v1[j]);
    }
    *(short8*)(xb + i) = r;
  } else if (bid < 2048 + 768) {
    int b = bid - 2048;
    transpose_tile(Wqkv, WtQkv, 1024, 3072, b % 48, b / 48, t);
  } else {
    int b = bid - 2816;
    transpose_tile(Wproj, WtP, 1024, 1024, b % 16, b / 16, t);
  }
}

// ---------------- GEMM: C[m][n] = A[m,:]·Bt[n,:] + bias[n] -------------------
// 3-BUFFER single-barrier async pipeline: per iteration {vmcnt(N)+barrier;
// issue DMA(it+2); frag reads + MFMA}. The barrier orders all waves' it-1
// reads before DMA(it+2) overwrites that buffer (WAR safe); the counted
// vmcnt verifies tile it landed while tile it+1's DMAs stay in flight.
// DMA lead time = 2 full iterations. One barrier per iteration.
// MODE 0 (TM=128): LDS-transposed coalesced epilogue -> Q (xQSCALE) as
//   [bh][t][64] (linear), K as [bh][t][64] with 16B-chunk XOR-swizzle
//   (chunk ^= row&7), V^T as [bh][64][t] PI-INTERLEAVED per 64-tile:
//   logical kv (kvh,quad,kvblk,r) stored at ((kvh*4+quad)^(d&7))*8 +
//   kvblk*4 + r -- so attn's PV B-fragment is ONE contiguous b128 in
//   exactly the pa8 element order.
// MODE 1 (TM=64): fp32 out row-major [M,Nn].
// Grid XCD-chunk swizzled (nwg % 8 == 0 -> bijective).
template <int MODE, int TM>
__global__ __launch_bounds__(256, (TM == 128) ? 3 : 2)
void gemm_bt(const bf16* __restrict__ A, const bf16* __restrict__ Bt,
             const float* __restrict__ bias, float* __restrict__ outp,
             bf16* __restrict__ Qd, bf16* __restrict__ Kd, bf16* __restrict__ Vt,
             int M, int Nn, int K) {
  constexpr int MI = TM / 32;
  constexpr int BUFE = TM * 32 + 4096;   // elements per staging buffer
  // 3 staging buffers; MODE-0 epilogue (<=9216 el) reuses the pool
  __shared__ __align__(16) bf16 smem[3 * BUFE];

  const int tid = threadIdx.x;
  const int wave = tid >> 6, lane = tid & 63;
  const int quad = lane >> 4, l16 = lane & 15;
  const int mw = (wave >> 1) * (TM / 2), nw = (wave & 1) * 64;

  // XCD-chunked swizzle of the linearized block id
  const int nwg = gridDim.x * gridDim.y;
  const int ord = blockIdx.y * gridDim.x + blockIdx.x;
  const int wg = (ord & 7) * (nwg >> 3) + (ord >> 3);
  const int m_blk = (wg / gridDim.x) * TM, n_blk = (wg % gridDim.x) * 128;

  f32x4 acc[MI][4];
#pragma unroll
  for (int i = 0; i < MI; ++i)
#pragma unroll
    for (int j = 0; j < 4; ++j) acc[i][j] = (f32x4){0.f, 0.f, 0.f, 0.f};

  const int rowA = lane >> 2, colA = (lane & 3) * 8;
  const int chunkB = wave * 2;
  const bf16* gB = Bt + (size_t)(n_blk + chunkB * 16 + rowA) * K + colA;
  const int chunkA = (TM == 128) ? wave * 2 : wave;
  const bf16* gA = A + (size_t)(m_blk + chunkA * 16 + rowA) * K + colA;

  // in-buffer LDS offsets (wave-uniform bases for the DMA)
  const int oA0 = chunkA * 512;
  const int oA1 = (chunkA + 1) * 512;             // unused for TM=64
  const int oB0 = TM * 32 + chunkB * 512;
  const int oB1 = TM * 32 + (chunkB + 1) * 512;

  const int nI = K >> 5;
  auto issue = [&](int t, int buf) {
    bf16* b = smem + buf * BUFE;
    const int kk = t << 5;
    gload_lds16(gA + kk, b + oA0);
    if (TM == 128) gload_lds16(gA + 16 * K + kk, b + oA1);
    gload_lds16(gB + kk, b + oB0);
    gload_lds16(gB + 16 * K + kk, b + oB1);
  };

  // prologue: issue DMA for tiles 0 and 1
  issue(0, 0);
  issue(1, 1);

  for (int it = 0; it < nI; ++it) {
    // 1. counted wait + barrier: tile it landed block-wide; tile it+1 rides on.
    //    Barrier also orders all waves' it-1 reads before the it+2 overwrite.
    if constexpr (TM == 128) VM4_BARRIER(); else VM3_BARRIER();

    // 2. issue DMA for tile it+2 (clamped dummy near the end)
    issue((it + 2 < nI) ? it + 2 : nI - 1, (it + 2) % 3);

    // 3. compute tile it
    bf16* bufc = smem + (it % 3) * BUFE;
    short8 af[MI], bfv[4];
#pragma unroll
    for (int i = 0; i < MI; ++i)
      af[i] = *(const short8*)&bufc[(mw + i * 16 + l16) * 32 + quad * 8];
#pragma unroll
    for (int j = 0; j < 4; ++j)
      bfv[j] = *(const short8*)&bufc[TM * 32 + (nw + j * 16 + l16) * 32 + quad * 8];
#pragma unroll
    for (int i = 0; i < MI; ++i)
#pragma unroll
      for (int j = 0; j < 4; ++j)
        acc[i][j] = __builtin_amdgcn_mfma_f32_16x16x32_bf16(af[i], bfv[j],
                                                            acc[i][j], 0, 0, 0);
  }

  // drain dummy prefetches before the epilogue reuses the pool
  DMA_BARRIER();

  if (MODE == 0) {
    // per-j bias for this wave's columns
    float bval[4];
#pragma unroll
    for (int j = 0; j < 4; ++j) bval[j] = bias[n_blk + nw + j * 16 + l16];

    const int part = n_blk >> 10;          // 0:q 1:k 2:v (block-uniform)
    const int b = m_blk >> 11;
    const int tloc = m_blk & 2047;
    const int h0 = (n_blk & 1023) >> 6;

#pragma unroll
    for (int p = 0; p < 2; ++p) {          // feature halves (64 cols = 1 head)
      __syncthreads();
      if ((nw >> 6) == p) {
        if (part == 2) {
          // V half-tile as [64 d][136 t], 8B-packed writes (r -> t contiguous)
#pragma unroll
          for (int i = 0; i < MI; ++i)
#pragma unroll
            for (int j = 0; j < 4; ++j) {
              const int dh = j * 16 + l16;
              const int t0 = mw + i * 16 + quad * 4;
              uint2 pk;
              pk.x = pack2_bf16(acc[i][j][0] + bval[j], acc[i][j][1] + bval[j]);
              pk.y = pack2_bf16(acc[i][j][2] + bval[j], acc[i][j][3] + bval[j]);
              *(uint2*)&smem[dh * 136 + t0] = pk;
            }
        } else {
          // Q/K half-tile as [128 t][72 d] (stride-72: conflict-free writes)
          const float sc = (part == 0) ? QSCALE : 1.0f;
#pragma unroll
          for (int i = 0; i < MI; ++i)
#pragma unroll
            for (int j = 0; j < 4; ++j) {
              const int d = j * 16 + l16;
              const int t0 = mw + i * 16 + quad * 4;
#pragma unroll
              for (int r = 0; r < 4; ++r)
                smem[(t0 + r) * 72 + d] =
                    __float2bfloat16((acc[i][j][r] + bval[j]) * sc);
            }
        }
      }
      __syncthreads();
      const size_t bh = (size_t)(b * 16 + h0 + p);
      if (part == 2) {
        // pi-interleaved store: 8 consecutive logical kv (one chunk c) split
        // into two 4-el groups at quads q0,q1; position within 64-tile =
        // ((kvh*4+q)^(d&7))*8 + kvblk*4 + r.
#pragma unroll
        for (int it = 0; it < 4; ++it) {
          const int dl = (tid >> 4) + it * 16;
          const int t8 = (tid & 15) * 8;
          short8 v = *(const short8*)&smem[dl * 136 + t8];
          const int c = (t8 & 63) >> 3;
          const int kvh = c >> 2, cc = c & 3;
          const int q0 = (cc * 2) & 3, q1 = (cc * 2 + 1) & 3;
          const int e2 = cc >> 1;            // kvblk of this group-pair
          const int x7 = dl & 7;
          const size_t rowb = (bh * 64 + dl) * 2048 + tloc + (t8 & 64);
          uint4 u = __builtin_bit_cast(uint4, v);
          *(uint2*)&Vt[rowb + (((kvh * 4 + q0) ^ x7) << 3) + e2 * 4] =
              (uint2){u.x, u.y};
          *(uint2*)&Vt[rowb + (((kvh * 4 + q1) ^ x7) << 3) + e2 * 4] =
              (uint2){u.z, u.w};
        }
      } else {
        bf16* dst = (part == 0) ? Qd : Kd;
#pragma unroll
        for (int it = 0; it < 4; ++it) {
          const int row = (tid >> 3) + it * 32;
          const int col8 = (tid & 7) * 8;
          // K gets the 16B-chunk XOR swizzle; Q stays linear
          const int c8 = (part == 1) ? (col8 ^ ((row & 7) << 3)) : col8;
          short8 v = *(const short8*)&smem[row * 72 + col8];
          *(short8*)&dst[(bh * 2048 + tloc + row) * 64 + c8] = v;
        }
      }
    }
  } else {
#pragma unroll
    for (int j = 0; j < 4; ++j) {
      const int ncol = n_blk + nw + j * 16 + l16;
      const float bval = bias[ncol];
#pragma unroll
      for (int i = 0; i < MI; ++i) {
        const int mrow0 = m_blk + mw + i * 16 + quad * 4;
#pragma unroll
        for (int r = 0; r < 4; ++r)
          outp[(size_t)(mrow0 + r) * Nn + ncol] = acc[i][j][r] + bval;
      }
    }
  }
}

// ---------------- flash attention: Qtile=64, KVtile=64, quadrant split -------
// R10 structure with single-b128 V fragments: V arrives pi-interleaved from
// gemm0 (position ((kvh*4+quad)^(d&7))*8 + kvblk*4 + r within each 64-tile),
// DMA'd verbatim, so each PV B-fragment is ONE ds_read_b128 in exactly pa8's
// element order -- no b64 pairs, no register reassembly. P in registers via
// pi-permuted K=32 PV; ones-MFMA row-sums; counted vmcnt(4); 32 KiB LDS ->
// 4 blocks/CU.
__global__ __launch_bounds__(256, 4)
void attn_kernel(const bf16* __restrict__ Qg, const bf16* __restrict__ Kg,
                 const bf16* __restrict__ Vt, bf16* __restrict__ yg) {
  // [0,16384): Ks[2][64][64]; [16384,32768): Vts[2][64][64].
  // Epilogue reuse: red = 16 KiB partials at 0; sred = 256 B at 16384.
  __shared__ __align__(16) char pool[32768];
  bf16* KsB = (bf16*)pool;
  bf16* VtsB = (bf16*)(pool + 16384);

  const int tid = threadIdx.x;
  const int wave = tid >> 6, lane = tid & 63;
  const int quad = lane >> 4, l16 = lane & 15;
  const int qh = wave & 1, kvh = wave >> 1;

  // XCD-chunked swizzle (nwg=1024, bijective): XCD k gets heads [4k,4k+4)
  const int bx0 = blockIdx.x;
  const int bx = ((bx0 & 7) << 7) | (bx0 >> 3);
  const int qt = bx & 31;                // 32 q-tiles of 64
  const int bh = bx >> 5;                // b*16 + h

  const bf16* Qb = Qg + ((size_t)bh * 2048 + qt * 64) * 64;
  const bf16* Kb = Kg + (size_t)bh * 2048 * 64;
  const bf16* Vtb = Vt + (size_t)bh * 64 * 2048;

  // Q fragments (linear layout, pre-scaled by QSCALE at gemm0)
  short8 qf[2][2];
#pragma unroll
  for (int qblk = 0; qblk < 2; ++qblk)
#pragma unroll
    for (int ks = 0; ks < 2; ++ks)
      qf[qblk][ks] = *(const short8*)(
          Qb + (size_t)(qh * 32 + qblk * 16 + l16) * 64 + ks * 32 + quad * 8);

  // async staging pointers: wave w issues instrs j=0,1 per tensor.
  const int sj = wave * 2;
  const bf16* kg = Kb + sj * 512 + lane * 8;                       // +kt*64+j*512
  const bf16* vg = Vtb + (size_t)(sj * 8 + (lane >> 3)) * 2048 +
                   (lane & 7) * 8;                                  // +kt+j*16384

  // fragment read offsets (XOR de-swizzle; conflict-spread)
  int kfo[2][2];
#pragma unroll
  for (int kvblk = 0; kvblk < 2; ++kvblk)
#pragma unroll
    for (int ks = 0; ks < 2; ++ks)
      kfo[kvblk][ks] = (kvh * 32 + kvblk * 16 + l16) * 64 +
                       (((ks * 4 + quad) ^ (l16 & 7)) << 3);
  int vro[4];
#pragma unroll
  for (int dblk = 0; dblk < 4; ++dblk) {
    const int d = dblk * 16 + l16;
    vro[dblk] = d * 64 + (((kvh * 4 + quad) ^ (d & 7)) << 3);
  }

  // preamble: issue DMA tile 0 -> buf0 (no wait; loop's barrier covers)
#pragma unroll
  for (int j = 0; j < 2; ++j) {
    gload_lds16(kg + j * 512, KsB + sj * 512 + j * 512);
    gload_lds16(vg + (size_t)j * 16384, VtsB + sj * 512 + j * 512);
  }

  f32x4 yacc[2][4];
#pragma unroll
  for (int qblk = 0; qblk < 2; ++qblk)
#pragma unroll
    for (int dblk = 0; dblk < 4; ++dblk)
      yacc[qblk][dblk] = (f32x4){0.f, 0.f, 0.f, 0.f};
  f32x4 sum_acc[2];
  sum_acc[0] = (f32x4){0.f, 0.f, 0.f, 0.f};
  sum_acc[1] = (f32x4){0.f, 0.f, 0.f, 0.f};

  uint4 ones_u;
  ones_u.x = ones_u.y = ones_u.z = ones_u.w = 0x3F803F80u;  // bf16 1.0 x8
  const short8 ones8 = __builtin_bit_cast(short8, ones_u);

  for (int kt = 0; kt < 2048; kt += 64) {
    const int cur = (kt >> 6) & 1;

    // 1. issue DMA for the next tile (clamped dummy on the last iteration)
    {
      const int kn = (kt + 64 < 2048) ? (kt + 64) : (2048 - 64);
      bf16* Kdst = KsB + (cur ^ 1) * 4096;
      bf16* Vdst = VtsB + (cur ^ 1) * 4096;
#pragma unroll
      for (int j = 0; j < 2; ++j) {
        gload_lds16(kg + kn * 64 + j * 512, Kdst + sj * 512 + j * 512);
        gload_lds16(vg + kn + (size_t)j * 16384, Vdst + sj * 512 + j * 512);
      }
    }

    // 2. counted wait + barrier: tile kt landed block-wide; prefetch rides on
    VM4_BARRIER();

    const bf16* KsC = KsB + cur * 4096;
    const bf16* VtsC = VtsB + cur * 4096;

    // 3. K fragments for this wave's kv-half
    short8 kf[2][2];
#pragma unroll
    for (int kvblk = 0; kvblk < 2; ++kvblk)
#pragma unroll
      for (int ks = 0; ks < 2; ++ks)
        kf[kvblk][ks] = *(const short8*)(KsC + kfo[kvblk][ks]);

    // 4. S^T + softmax -> pa8; row-sum via ones-MFMA (no VALU adds)
    short8 pa8[2];
#pragma unroll
    for (int qblk = 0; qblk < 2; ++qblk) {
      f32x4 s0 = (f32x4){0.f, 0.f, 0.f, 0.f};
      f32x4 s1 = (f32x4){0.f, 0.f, 0.f, 0.f};
      s0 = __builtin_amdgcn_mfma_f32_16x16x32_bf16(kf[0][0], qf[qblk][0], s0, 0, 0, 0);
      s0 = __builtin_amdgcn_mfma_f32_16x16x32_bf16(kf[0][1], qf[qblk][1], s0, 0, 0, 0);
      s1 = __builtin_amdgcn_mfma_f32_16x16x32_bf16(kf[1][0], qf[qblk][0], s1, 0, 0, 0);
      s1 = __builtin_amdgcn_mfma_f32_16x16x32_bf16(kf[1][1], qf[qblk][1], s1, 0, 0, 0);
      float p0 = fast_exp2(s0[0]), p1 = fast_exp2(s0[1]);
      float p2 = fast_exp2(s0[2]), p3 = fast_exp2(s0[3]);
      float p4 = fast_exp2(s1[0]), p5 = fast_exp2(s1[1]);
      float p6 = fast_exp2(s1[2]), p7 = fast_exp2(s1[3]);
      uint4 u;
      u.x = pack2_bf16(p0, p1);
      u.y = pack2_bf16(p2, p3);
      u.z = pack2_bf16(p4, p5);
      u.w = pack2_bf16(p6, p7);
      pa8[qblk] = __builtin_bit_cast(short8, u);
      sum_acc[qblk] = __builtin_amdgcn_mfma_f32_16x16x32_bf16(
          pa8[qblk], ones8, sum_acc[qblk], 0, 0, 0);
    }

    // 5. Y += P·V, K=32 MFMA with single-b128 pi-interleaved V fragments
#pragma unroll
    for (int dblk = 0; dblk < 4; ++dblk) {
      short8 vb8 = *(const short8*)(VtsC + vro[dblk]);
      yacc[0][dblk] = __builtin_amdgcn_mfma_f32_16x16x32_bf16(
          pa8[0], vb8, yacc[0][dblk], 0, 0, 0);
      yacc[1][dblk] = __builtin_amdgcn_mfma_f32_16x16x32_bf16(
          pa8[1], vb8, yacc[1][dblk], 0, 0, 0);
    }

    // 6. WAR barrier: reads of buf[cur] done before next iter overwrites it
    LDSR_BARRIER();
  }

  // ---- epilogue: drain dummy prefetch, then reduce kv-halves ----
  DMA_BARRIER();
  float* red = (float*)pool;                 // 16384 B Y-partials
  float* sred = (float*)(pool + 16384);      // 256 B sums
  if (kvh == 1) {
#pragma unroll
    for (int qblk = 0; qblk < 2; ++qblk) {
#pragma unroll
      for (int dblk = 0; dblk < 4; ++dblk) {
        const int f = (qh * 2 + qblk) * 4 + dblk;
        *(f32x4*)&red[(f * 64 + quad * 16 + l16) * 4] = yacc[qblk][dblk];
      }
      if (l16 == 0)
        *(f32x4*)&sred[(qh * 2 + qblk) * 16 + quad * 4] = sum_acc[qblk];
    }
  }
  __syncthreads();
  if (kvh == 0) {
    const int b = bh >> 4, h = bh & 15;
    const size_t rowbase = (size_t)b * 2048 + qt * 64;
#pragma unroll
    for (int qblk = 0; qblk < 2; ++qblk) {
      f32x4 sp = *(const f32x4*)&sred[(qh * 2 + qblk) * 16 + quad * 4];
#pragma unroll
      for (int dblk = 0; dblk < 4; ++dblk) {
        const int f = (qh * 2 + qblk) * 4 + dblk;
        f32x4 o = *(const f32x4*)&red[(f * 64 + quad * 16 + l16) * 4];
#pragma unroll
        for (int r = 0; r < 4; ++r) yacc[qblk][dblk][r] += o[r];
      }
#pragma unroll
      for (int r = 0; r < 4; ++r) {
        const float inv = 1.f / (sum_acc[qblk][r] + sp[r]);
        const int rr = qh * 32 + qblk * 16 + quad * 4 + r;
#pragma unroll
        for (int dblk = 0; dblk < 4; ++dblk)
          yg[(rowbase + rr) * 1024 + h * 64 + dblk * 16 + l16] =
              __float2bfloat16(yacc[qblk][dblk][r] * inv);
      }
    }
  }
}

// ---------------- launch ----------------
extern "C" void kernel_launch(void* const* d_in, const int* in_sizes, int n_in,
                              void* d_out, int out_size, void* d_ws, size_t ws_size,
                              hipStream_t stream) {
  const float* x = (const float*)d_in[0];      // [4096, 1024] fp32
  const float* Wqkv = (const float*)d_in[1];   // [1024, 3072] fp32
  const float* bqkv = (const float*)d_in[2];   // [3072] fp32
  const float* Wproj = (const float*)d_in[3];  // [1024, 1024] fp32
  const float* bproj = (const float*)d_in[4];  // [1024] fp32
  float* out = (float*)d_out;                  // [4096, 1024] fp32

  if (ws_size < (size_t)40 * 1024 * 1024) return;

  char* ws = (char*)d_ws;
  bf16* xb    = (bf16*)(ws + 0);             // [4096,1024] = 8 MiB
  bf16* yd    = (bf16*)(ws + 0);             // aliases xb (dead after gemm0)
  bf16* WtQkv = (bf16*)(ws + 8388608);       // [3072,1024] = 6 MiB
  bf16* WtP   = (bf16*)(ws + 14680064);      // [1024,1024] = 2 MiB
  bf16* Qd    = (bf16*)(ws + 16777216);      // [32,2048,64] = 8 MiB (pre-scaled)
  bf16* Kd    = (bf16*)(ws + 25165824);      // 8 MiB (chunk-swizzled rows)
  bf16* Vten  = (bf16*)(ws + 33554432);      // [32,64,2048] = 8 MiB (pi-interleaved)

  prep_k<<<3072, 256, 0, stream>>>(x, xb, Wqkv, WtQkv, Wproj, WtP);
  gemm_bt<0, 128><<<dim3(24, 32), 256, 0, stream>>>(
      xb, WtQkv, bqkv, nullptr, Qd, Kd, Vten, 4096, 3072, 1024);
  attn_kernel<<<dim3(1024), 256, 0, stream>>>(Qd, Kd, Vten, yd);
  gemm_bt<1, 64><<<dim3(8, 64), 256, 0, stream>>>(
      yd, WtP, bproj, out, nullptr, nullptr, nullptr, 4096, 1024, 1024);
}

// Round 12
// 180.533 us; speedup vs baseline: 1.0362x; 1.0001x over previous
//
#include <hip/hip_runtime.h>
#include <hip/hip_bf16.h>
#include <stdint.h>

typedef __hip_bfloat16 bf16;
typedef __attribute__((ext_vector_type(8))) short short8;   // 8 bf16
typedef __attribute__((ext_vector_type(4))) float f32x4;

#define QSCALE 0.18033688011f   // 0.125 * log2(e), folded into Q at gemm0

// ---- 1-instr helpers ----
__device__ __forceinline__ float fast_exp2(float x) {
#if __has_builtin(__builtin_amdgcn_exp2f)
  return __builtin_amdgcn_exp2f(x);
#else
  return exp2f(x);
#endif
}

__device__ __forceinline__ uint32_t pack2_bf16(float a, float b) {
#if __has_builtin(__builtin_amdgcn_cvt_pk_bf16_f32)
  typedef __attribute__((ext_vector_type(2))) __bf16 bf16x2;
  bf16x2 v = __builtin_amdgcn_cvt_pk_bf16_f32(a, b);
  return __builtin_bit_cast(uint32_t, v);
#else
  uint32_t ua = __builtin_bit_cast(uint32_t, a);
  uint32_t ub = __builtin_bit_cast(uint32_t, b);
  ua += 0x7FFF + ((ua >> 16) & 1);   // RNE
  ub += 0x7FFF + ((ub >> 16) & 1);
  return (ua >> 16) | (ub & 0xFFFF0000u);
#endif
}

// async global->LDS, 16B per lane: g is the PER-LANE global pointer,
// l is the WAVE-UNIFORM LDS base (lane lands at l + lane*16B).
__device__ __forceinline__ void gload_lds16(const bf16* g, bf16* l) {
#if __has_builtin(__builtin_amdgcn_global_load_lds)
  __builtin_amdgcn_global_load_lds(
      (const __attribute__((address_space(1))) void*)(uintptr_t)g,
      (__attribute__((address_space(3))) void*)(uint32_t)(uintptr_t)l,
      16, 0, 0);
#else
  int lane = threadIdx.x & 63;
  *(short8*)(l + lane * 8) = *(const short8*)(g + lane * 8);
#endif
}

#define SETPRIO1() __builtin_amdgcn_s_setprio(1)
#define SETPRIO0() __builtin_amdgcn_s_setprio(0)

// T4 counted-vmcnt barriers: each wave verifies its OWN older DMAs are done
// BEFORE the barrier -> after the barrier the collective tile has landed,
// while the just-issued prefetch DMAs stay in flight.
#define VM4_BARRIER() \
  asm volatile("s_waitcnt vmcnt(4)\n\ts_barrier" ::: "memory")
#define VM3_BARRIER() \
  asm volatile("s_waitcnt vmcnt(3)\n\ts_barrier" ::: "memory")
// WAR-protect barrier (attn 2-buffer loop): reads done before next overwrite.
#define LDSR_BARRIER() \
  asm volatile("s_waitcnt lgkmcnt(0)\n\ts_barrier" ::: "memory")
// full drain (epilogue entry: dummy prefetches may still target the pool)
#define DMA_BARRIER() \
  asm volatile("s_waitcnt vmcnt(0) lgkmcnt(0)\n\ts_barrier" ::: "memory")

// ---- fp32->bf16 transpose tile body (64x64) ----
__device__ __forceinline__ void transpose_tile(const float* __restrict__ in,
                                               bf16* __restrict__ out,
                                               int R, int C, int bx, int by,
                                               bf16 (*t)[72]) {
  const int r0 = by * 64, c0 = bx * 64;
  const int rr = threadIdx.x >> 3, cc = (threadIdx.x & 7) * 8;
#pragma unroll
  for (int rep = 0; rep < 2; ++rep) {
    int y = rr + rep * 32;
    const float* p = in + (size_t)(r0 + y) * C + c0 + cc;
    f32x4 v0 = *(const f32x4*)p;
    f32x4 v1 = *(const f32x4*)(p + 4);
#pragma unroll
    for (int j = 0; j < 4; ++j) {
      t[cc + j][y] = __float2bfloat16(v0[j]);
      t[cc + 4 + j][y] = __float2bfloat16(v1[j]);
    }
  }
  __syncthreads();
#pragma unroll
  for (int rep = 0; rep < 2; ++rep) {
    int y = rr + rep * 32;
    short8 v = *(const short8*)&t[y][cc];
    *(short8*)(out + (size_t)(c0 + y) * R + r0 + cc) = v;
  }
}

// ---- fused prep: x->bf16 (blocks 0..2047), Wqkv^T (2048..2815),
//      Wproj^T (2816..3071) ----
__global__ __launch_bounds__(256)
void prep_k(const float* __restrict__ x, bf16* __restrict__ xb,
            const float* __restrict__ Wqkv, bf16* __restrict__ WtQkv,
            const float* __restrict__ Wproj, bf16* __restrict__ WtP) {
  __shared__ __align__(16) bf16 t[64][72];
  const int bid = blockIdx.x;
  if (bid < 2048) {
    int i = (bid * 256 + threadIdx.x) * 8;
    f32x4 v0 = *(const f32x4*)(x + i);
    f32x4 v1 = *(const f32x4*)(x + i + 4);
    short8 r;
    bf16* rb = (bf16*)&r;
#pragma unroll
    for (int j = 0; j < 4; ++j) {
      rb[j] = __float2bfloat16(v0[j]);
      rb[4 + j] = __float2bfloat16(v1[j]);
    }
    *(short8*)(xb + i) = r;
  } else if (bid < 2048 + 768) {
    int b = bid - 2048;
    transpose_tile(Wqkv, WtQkv, 1024, 3072, b % 48, b / 48, t);
  } else {
    int b = bid - 2816;
    transpose_tile(Wproj, WtP, 1024, 1024, b % 16, b / 16, t);
  }
}

// ---------------- GEMM: C[m][n] = A[m,:]·Bt[n,:] + bias[n] -------------------
// 3-BUFFER single-barrier async pipeline: per iteration {vmcnt(N)+barrier;
// issue DMA(it+2); frag reads + MFMA}. The barrier orders all waves' it-1
// reads before DMA(it+2) overwrites that buffer (WAR safe); the counted
// vmcnt verifies tile it landed while tile it+1's DMAs stay in flight.
// MFMA cluster wrapped in s_setprio(1) (T5): MFMA-entering waves win CU
// arbitration over other blocks' staging/VALU waves.
// MODE 0 (TM=128): LDS-transposed coalesced epilogue -> Q (xQSCALE) as
//   [bh][t][64] (linear), K as [bh][t][64] with 16B-chunk XOR-swizzle
//   (chunk ^= row&7), V^T as [bh][64][t] PI-INTERLEAVED per 64-tile:
//   logical kv (kvh,quad,kvblk,r) stored at ((kvh*4+quad)^(d&7))*8 +
//   kvblk*4 + r -- so attn's PV B-fragment is ONE contiguous b128 in
//   exactly the pa8 element order.
// MODE 1 (TM=64): fp32 out row-major [M,Nn].
// Grid XCD-chunk swizzled (nwg % 8 == 0 -> bijective).
template <int MODE, int TM>
__global__ __launch_bounds__(256, (TM == 128) ? 3 : 2)
void gemm_bt(const bf16* __restrict__ A, const bf16* __restrict__ Bt,
             const float* __restrict__ bias, float* __restrict__ outp,
             bf16* __restrict__ Qd, bf16* __restrict__ Kd, bf16* __restrict__ Vt,
             int M, int Nn, int K) {
  constexpr int MI = TM / 32;
  constexpr int BUFE = TM * 32 + 4096;   // elements per staging buffer
  // 3 staging buffers; MODE-0 epilogue (<=9216 el) reuses the pool
  __shared__ __align__(16) bf16 smem[3 * BUFE];

  const int tid = threadIdx.x;
  const int wave = tid >> 6, lane = tid & 63;
  const int quad = lane >> 4, l16 = lane & 15;
  const int mw = (wave >> 1) * (TM / 2), nw = (wave & 1) * 64;

  // XCD-chunked swizzle of the linearized block id
  const int nwg = gridDim.x * gridDim.y;
  const int ord = blockIdx.y * gridDim.x + blockIdx.x;
  const int wg = (ord & 7) * (nwg >> 3) + (ord >> 3);
  const int m_blk = (wg / gridDim.x) * TM, n_blk = (wg % gridDim.x) * 128;

  f32x4 acc[MI][4];
#pragma unroll
  for (int i = 0; i < MI; ++i)
#pragma unroll
    for (int j = 0; j < 4; ++j) acc[i][j] = (f32x4){0.f, 0.f, 0.f, 0.f};

  const int rowA = lane >> 2, colA = (lane & 3) * 8;
  const int chunkB = wave * 2;
  const bf16* gB = Bt + (size_t)(n_blk + chunkB * 16 + rowA) * K + colA;
  const int chunkA = (TM == 128) ? wave * 2 : wave;
  const bf16* gA = A + (size_t)(m_blk + chunkA * 16 + rowA) * K + colA;

  // in-buffer LDS offsets (wave-uniform bases for the DMA)
  const int oA0 = chunkA * 512;
  const int oA1 = (chunkA + 1) * 512;             // unused for TM=64
  const int oB0 = TM * 32 + chunkB * 512;
  const int oB1 = TM * 32 + (chunkB + 1) * 512;

  const int nI = K >> 5;
  auto issue = [&](int t, int buf) {
    bf16* b = smem + buf * BUFE;
    const int kk = t << 5;
    gload_lds16(gA + kk, b + oA0);
    if (TM == 128) gload_lds16(gA + 16 * K + kk, b + oA1);
    gload_lds16(gB + kk, b + oB0);
    gload_lds16(gB + 16 * K + kk, b + oB1);
  };

  // prologue: issue DMA for tiles 0 and 1
  issue(0, 0);
  issue(1, 1);

  for (int it = 0; it < nI; ++it) {
    // 1. counted wait + barrier: tile it landed block-wide; tile it+1 rides on.
    //    Barrier also orders all waves' it-1 reads before the it+2 overwrite.
    if constexpr (TM == 128) VM4_BARRIER(); else VM3_BARRIER();

    // 2. issue DMA for tile it+2 (clamped dummy near the end)
    issue((it + 2 < nI) ? it + 2 : nI - 1, (it + 2) % 3);

    // 3. compute tile it (setprio: MFMA waves win arbitration)
    bf16* bufc = smem + (it % 3) * BUFE;
    short8 af[MI], bfv[4];
#pragma unroll
    for (int i = 0; i < MI; ++i)
      af[i] = *(const short8*)&bufc[(mw + i * 16 + l16) * 32 + quad * 8];
#pragma unroll
    for (int j = 0; j < 4; ++j)
      bfv[j] = *(const short8*)&bufc[TM * 32 + (nw + j * 16 + l16) * 32 + quad * 8];
    SETPRIO1();
#pragma unroll
    for (int i = 0; i < MI; ++i)
#pragma unroll
      for (int j = 0; j < 4; ++j)
        acc[i][j] = __builtin_amdgcn_mfma_f32_16x16x32_bf16(af[i], bfv[j],
                                                            acc[i][j], 0, 0, 0);
    SETPRIO0();
  }

  // drain dummy prefetches before the epilogue reuses the pool
  DMA_BARRIER();

  if (MODE == 0) {
    // per-j bias for this wave's columns
    float bval[4];
#pragma unroll
    for (int j = 0; j < 4; ++j) bval[j] = bias[n_blk + nw + j * 16 + l16];

    const int part = n_blk >> 10;          // 0:q 1:k 2:v (block-uniform)
    const int b = m_blk >> 11;
    const int tloc = m_blk & 2047;
    const int h0 = (n_blk & 1023) >> 6;

#pragma unroll
    for (int p = 0; p < 2; ++p) {          // feature halves (64 cols = 1 head)
      __syncthreads();
      if ((nw >> 6) == p) {
        if (part == 2) {
          // V half-tile as [64 d][136 t], 8B-packed writes (r -> t contiguous)
#pragma unroll
          for (int i = 0; i < MI; ++i)
#pragma unroll
            for (int j = 0; j < 4; ++j) {
              const int dh = j * 16 + l16;
              const int t0 = mw + i * 16 + quad * 4;
              uint2 pk;
              pk.x = pack2_bf16(acc[i][j][0] + bval[j], acc[i][j][1] + bval[j]);
              pk.y = pack2_bf16(acc[i][j][2] + bval[j], acc[i][j][3] + bval[j]);
              *(uint2*)&smem[dh * 136 + t0] = pk;
            }
        } else {
          // Q/K half-tile as [128 t][72 d] (stride-72: conflict-free writes)
          const float sc = (part == 0) ? QSCALE : 1.0f;
#pragma unroll
          for (int i = 0; i < MI; ++i)
#pragma unroll
            for (int j = 0; j < 4; ++j) {
              const int d = j * 16 + l16;
              const int t0 = mw + i * 16 + quad * 4;
#pragma unroll
              for (int r = 0; r < 4; ++r)
                smem[(t0 + r) * 72 + d] =
                    __float2bfloat16((acc[i][j][r] + bval[j]) * sc);
            }
        }
      }
      __syncthreads();
      const size_t bh = (size_t)(b * 16 + h0 + p);
      if (part == 2) {
        // pi-interleaved store: 8 consecutive logical kv (one chunk c) split
        // into two 4-el groups at quads q0,q1; position within 64-tile =
        // ((kvh*4+q)^(d&7))*8 + kvblk*4 + r.
#pragma unroll
        for (int it = 0; it < 4; ++it) {
          const int dl = (tid >> 4) + it * 16;
          const int t8 = (tid & 15) * 8;
          short8 v = *(const short8*)&smem[dl * 136 + t8];
          const int c = (t8 & 63) >> 3;
          const int kvh = c >> 2, cc = c & 3;
          const int q0 = (cc * 2) & 3, q1 = (cc * 2 + 1) & 3;
          const int e2 = cc >> 1;            // kvblk of this group-pair
          const int x7 = dl & 7;
          const size_t rowb = (bh * 64 + dl) * 2048 + tloc + (t8 & 64);
          uint4 u = __builtin_bit_cast(uint4, v);
          *(uint2*)&Vt[rowb + (((kvh * 4 + q0) ^ x7) << 3) + e2 * 4] =
              (uint2){u.x, u.y};
          *(uint2*)&Vt[rowb + (((kvh * 4 + q1) ^ x7) << 3) + e2 * 4] =
              (uint2){u.z, u.w};
        }
      } else {
        bf16* dst = (part == 0) ? Qd : Kd;
#pragma unroll
        for (int it = 0; it < 4; ++it) {
          const int row = (tid >> 3) + it * 32;
          const int col8 = (tid & 7) * 8;
          // K gets the 16B-chunk XOR swizzle; Q stays linear
          const int c8 = (part == 1) ? (col8 ^ ((row & 7) << 3)) : col8;
          short8 v = *(const short8*)&smem[row * 72 + col8];
          *(short8*)&dst[(bh * 2048 + tloc + row) * 64 + c8] = v;
        }
      }
    }
  } else {
#pragma unroll
    for (int j = 0; j < 4; ++j) {
      const int ncol = n_blk + nw + j * 16 + l16;
      const float bval = bias[ncol];
#pragma unroll
      for (int i = 0; i < MI; ++i) {
        const int mrow0 = m_blk + mw + i * 16 + quad * 4;
#pragma unroll
        for (int r = 0; r < 4; ++r)
          outp[(size_t)(mrow0 + r) * Nn + ncol] = acc[i][j][r] + bval;
      }
    }
  }
}

// ---------------- flash attention: Qtile=64, KVtile=64, quadrant split -------
// R11 structure (bank-conflict-free, counted vmcnt) + s_setprio(1) around
// both MFMA clusters (T5, m191: helps when independent blocks sit at
// different phases -- the MFMA-entering wave outbids other blocks'
// exp/LDS-issuing waves for CU issue slots).
__global__ __launch_bounds__(256, 4)
void attn_kernel(const bf16* __restrict__ Qg, const bf16* __restrict__ Kg,
                 const bf16* __restrict__ Vt, bf16* __restrict__ yg) {
  // [0,16384): Ks[2][64][64]; [16384,32768): Vts[2][64][64].
  // Epilogue reuse: red = 16 KiB partials at 0; sred = 256 B at 16384.
  __shared__ __align__(16) char pool[32768];
  bf16* KsB = (bf16*)pool;
  bf16* VtsB = (bf16*)(pool + 16384);

  const int tid = threadIdx.x;
  const int wave = tid >> 6, lane = tid & 63;
  const int quad = lane >> 4, l16 = lane & 15;
  const int qh = wave & 1, kvh = wave >> 1;

  // XCD-chunked swizzle (nwg=1024, bijective): XCD k gets heads [4k,4k+4)
  const int bx0 = blockIdx.x;
  const int bx = ((bx0 & 7) << 7) | (bx0 >> 3);
  const int qt = bx & 31;                // 32 q-tiles of 64
  const int bh = bx >> 5;                // b*16 + h

  const bf16* Qb = Qg + ((size_t)bh * 2048 + qt * 64) * 64;
  const bf16* Kb = Kg + (size_t)bh * 2048 * 64;
  const bf16* Vtb = Vt + (size_t)bh * 64 * 2048;

  // Q fragments (linear layout, pre-scaled by QSCALE at gemm0)
  short8 qf[2][2];
#pragma unroll
  for (int qblk = 0; qblk < 2; ++qblk)
#pragma unroll
    for (int ks = 0; ks < 2; ++ks)
      qf[qblk][ks] = *(const short8*)(
          Qb + (size_t)(qh * 32 + qblk * 16 + l16) * 64 + ks * 32 + quad * 8);

  // async staging pointers: wave w issues instrs j=0,1 per tensor.
  const int sj = wave * 2;
  const bf16* kg = Kb + sj * 512 + lane * 8;                       // +kt*64+j*512
  const bf16* vg = Vtb + (size_t)(sj * 8 + (lane >> 3)) * 2048 +
                   (lane & 7) * 8;                                  // +kt+j*16384

  // fragment read offsets (XOR de-swizzle; conflict-free)
  int kfo[2][2];
#pragma unroll
  for (int kvblk = 0; kvblk < 2; ++kvblk)
#pragma unroll
    for (int ks = 0; ks < 2; ++ks)
      kfo[kvblk][ks] = (kvh * 32 + kvblk * 16 + l16) * 64 +
                       (((ks * 4 + quad) ^ (l16 & 7)) << 3);
  int vro[4];
#pragma unroll
  for (int dblk = 0; dblk < 4; ++dblk) {
    const int d = dblk * 16 + l16;
    vro[dblk] = d * 64 + (((kvh * 4 + quad) ^ (d & 7)) << 3);
  }

  // preamble: issue DMA tile 0 -> buf0 (no wait; loop's barrier covers)
#pragma unroll
  for (int j = 0; j < 2; ++j) {
    gload_lds16(kg + j * 512, KsB + sj * 512 + j * 512);
    gload_lds16(vg + (size_t)j * 16384, VtsB + sj * 512 + j * 512);
  }

  f32x4 yacc[2][4];
#pragma unroll
  for (int qblk = 0; qblk < 2; ++qblk)
#pragma unroll
    for (int dblk = 0; dblk < 4; ++dblk)
      yacc[qblk][dblk] = (f32x4){0.f, 0.f, 0.f, 0.f};
  f32x4 sum_acc[2];
  sum_acc[0] = (f32x4){0.f, 0.f, 0.f, 0.f};
  sum_acc[1] = (f32x4){0.f, 0.f, 0.f, 0.f};

  uint4 ones_u;
  ones_u.x = ones_u.y = ones_u.z = ones_u.w = 0x3F803F80u;  // bf16 1.0 x8
  const short8 ones8 = __builtin_bit_cast(short8, ones_u);

  for (int kt = 0; kt < 2048; kt += 64) {
    const int cur = (kt >> 6) & 1;

    // 1. issue DMA for the next tile (clamped dummy on the last iteration)
    {
      const int kn = (kt + 64 < 2048) ? (kt + 64) : (2048 - 64);
      bf16* Kdst = KsB + (cur ^ 1) * 4096;
      bf16* Vdst = VtsB + (cur ^ 1) * 4096;
#pragma unroll
      for (int j = 0; j < 2; ++j) {
        gload_lds16(kg + kn * 64 + j * 512, Kdst + sj * 512 + j * 512);
        gload_lds16(vg + kn + (size_t)j * 16384, Vdst + sj * 512 + j * 512);
      }
    }

    // 2. counted wait + barrier: tile kt landed block-wide; prefetch rides on
    VM4_BARRIER();

    const bf16* KsC = KsB + cur * 4096;
    const bf16* VtsC = VtsB + cur * 4096;

    // 3. K fragments for this wave's kv-half
    short8 kf[2][2];
#pragma unroll
    for (int kvblk = 0; kvblk < 2; ++kvblk)
#pragma unroll
      for (int ks = 0; ks < 2; ++ks)
        kf[kvblk][ks] = *(const short8*)(KsC + kfo[kvblk][ks]);

    // 4. S^T + softmax -> pa8; row-sum via ones-MFMA (no VALU adds)
    short8 pa8[2];
    f32x4 s0[2], s1[2];
    SETPRIO1();
#pragma unroll
    for (int qblk = 0; qblk < 2; ++qblk) {
      f32x4 a0 = (f32x4){0.f, 0.f, 0.f, 0.f};
      f32x4 a1 = (f32x4){0.f, 0.f, 0.f, 0.f};
      a0 = __builtin_amdgcn_mfma_f32_16x16x32_bf16(kf[0][0], qf[qblk][0], a0, 0, 0, 0);
      a0 = __builtin_amdgcn_mfma_f32_16x16x32_bf16(kf[0][1], qf[qblk][1], a0, 0, 0, 0);
      a1 = __builtin_amdgcn_mfma_f32_16x16x32_bf16(kf[1][0], qf[qblk][0], a1, 0, 0, 0);
      a1 = __builtin_amdgcn_mfma_f32_16x16x32_bf16(kf[1][1], qf[qblk][1], a1, 0, 0, 0);
      s0[qblk] = a0;
      s1[qblk] = a1;
    }
    SETPRIO0();
#pragma unroll
    for (int qblk = 0; qblk < 2; ++qblk) {
      float p0 = fast_exp2(s0[qblk][0]), p1 = fast_exp2(s0[qblk][1]);
      float p2 = fast_exp2(s0[qblk][2]), p3 = fast_exp2(s0[qblk][3]);
      float p4 = fast_exp2(s1[qblk][0]), p5 = fast_exp2(s1[qblk][1]);
      float p6 = fast_exp2(s1[qblk][2]), p7 = fast_exp2(s1[qblk][3]);
      uint4 u;
      u.x = pack2_bf16(p0, p1);
      u.y = pack2_bf16(p2, p3);
      u.z = pack2_bf16(p4, p5);
      u.w = pack2_bf16(p6, p7);
      pa8[qblk] = __builtin_bit_cast(short8, u);
      sum_acc[qblk] = __builtin_amdgcn_mfma_f32_16x16x32_bf16(
          pa8[qblk], ones8, sum_acc[qblk], 0, 0, 0);
    }

    // 5. Y += P·V, K=32 MFMA with single-b128 pi-interleaved V fragments
    SETPRIO1();
#pragma unroll
    for (int dblk = 0; dblk < 4; ++dblk) {
      short8 vb8 = *(const short8*)(VtsC + vro[dblk]);
      yacc[0][dblk] = __builtin_amdgcn_mfma_f32_16x16x32_bf16(
          pa8[0], vb8, yacc[0][dblk], 0, 0, 0);
      yacc[1][dblk] = __builtin_amdgcn_mfma_f32_16x16x32_bf16(
          pa8[1], vb8, yacc[1][dblk], 0, 0, 0);
    }
    SETPRIO0();

    // 6. WAR barrier: reads of buf[cur] done before next iter overwrites it
    LDSR_BARRIER();
  }

  // ---- epilogue: drain dummy prefetch, then reduce kv-halves ----
  DMA_BARRIER();
  float* red = (float*)pool;                 // 16384 B Y-partials
  float* sred = (float*)(pool + 16384);      // 256 B sums
  if (kvh == 1) {
#pragma unroll
    for (int qblk = 0; qblk < 2; ++qblk) {
#pragma unroll
      for (int dblk = 0; dblk < 4; ++dblk) {
        const int f = (qh * 2 + qblk) * 4 + dblk;
        *(f32x4*)&red[(f * 64 + quad * 16 + l16) * 4] = yacc[qblk][dblk];
      }
      if (l16 == 0)
        *(f32x4*)&sred[(qh * 2 + qblk) * 16 + quad * 4] = sum_acc[qblk];
    }
  }
  __syncthreads();
  if (kvh == 0) {
    const int b = bh >> 4, h = bh & 15;
    const size_t rowbase = (size_t)b * 2048 + qt * 64;
#pragma unroll
    for (int qblk = 0; qblk < 2; ++qblk) {
      f32x4 sp = *(const f32x4*)&sred[(qh * 2 + qblk) * 16 + quad * 4];
#pragma unroll
      for (int dblk = 0; dblk < 4; ++dblk) {
        const int f = (qh * 2 + qblk) * 4 + dblk;
        f32x4 o = *(const f32x4*)&red[(f * 64 + quad * 16 + l16) * 4];
#pragma unroll
        for (int r = 0; r < 4; ++r) yacc[qblk][dblk][r] += o[r];
      }
#pragma unroll
      for (int r = 0; r < 4; ++r) {
        const float inv = 1.f / (sum_acc[qblk][r] + sp[r]);
        const int rr = qh * 32 + qblk * 16 + quad * 4 + r;
#pragma unroll
        for (int dblk = 0; dblk < 4; ++dblk)
          yg[(rowbase + rr) * 1024 + h * 64 + dblk * 16 + l16] =
              __float2bfloat16(yacc[qblk][dblk][r] * inv);
      }
    }
  }
}

// ---------------- launch ----------------
extern "C" void kernel_launch(void* const* d_in, const int* in_sizes, int n_in,
                              void* d_out, int out_size, void* d_ws, size_t ws_size,
                              hipStream_t stream) {
  const float* x = (const float*)d_in[0];      // [4096, 1024] fp32
  const float* Wqkv = (const float*)d_in[1];   // [1024, 3072] fp32
  const float* bqkv = (const float*)d_in[2];   // [3072] fp32
  const float* Wproj = (const float*)d_in[3];  // [1024, 1024] fp32
  const float* bproj = (const float*)d_in[4];  // [1024] fp32
  float* out = (float*)d_out;                  // [4096, 1024] fp32

  if (ws_size < (size_t)40 * 1024 * 1024) return;

  char* ws = (char*)d_ws;
  bf16* xb    = (bf16*)(ws + 0);             // [4096,1024] = 8 MiB
  bf16* yd    = (bf16*)(ws + 0);             // aliases xb (dead after gemm0)
  bf16* WtQkv = (bf16*)(ws + 8388608);       // [3072,1024] = 6 MiB
  bf16* WtP   = (bf16*)(ws + 14680064);      // [1024,1024] = 2 MiB
  bf16* Qd    = (bf16*)(ws + 16777216);      // [32,2048,64] = 8 MiB (pre-scaled)
  bf16* Kd    = (bf16*)(ws + 25165824);      // 8 MiB (chunk-swizzled rows)
  bf16* Vten  = (bf16*)(ws + 33554432);      // [32,64,2048] = 8 MiB (pi-interleaved)

  prep_k<<<3072, 256, 0, stream>>>(x, xb, Wqkv, WtQkv, Wproj, WtP);
  gemm_bt<0, 128><<<dim3(24, 32), 256, 0, stream>>>(
      xb, WtQkv, bqkv, nullptr, Qd, Kd, Vten, 4096, 3072, 1024);
  attn_kernel<<<dim3(1024), 256, 0, stream>>>(Qd, Kd, Vten, yd);
  gemm_bt<1, 64><<<dim3(8, 64), 256, 0, stream>>>(
      yd, WtP, bproj, out, nullptr, nullptr, nullptr, 4096, 1024, 1024);
}